// Round 8
// baseline (704.689 us; speedup 1.0000x reference)
//
#include <hip/hip_runtime.h>
#include <hip/hip_bf16.h>
#include <hip/hip_fp16.h>

#define N_NODES 25000
#define M_PAD   25024            // multiple of 16 (1564 tiles)
#define N_EDGES 300000
#define IN_DIM  32
#define EDFD    16
#define HIDD    256
#define HEADS   4
#define NACT    16
#define NGRAPH  64
#define KWIRE   1024
#define POOL_NB 64               // nodes per pooling block

typedef __attribute__((ext_vector_type(8))) short short8v;
typedef __attribute__((ext_vector_type(4))) float f32x4;

// ---------------------------------------------------------------- helpers
__device__ __forceinline__ float leaky(float v) { return v > 0.f ? v : 0.2f * v; }
__device__ __forceinline__ unsigned short f2bf(float f) {
    unsigned int u = __float_as_uint(f);
    u += 0x7fff + ((u >> 16) & 1);           // round-to-nearest-even
    return (unsigned short)(u >> 16);
}
__device__ __forceinline__ float bf2f(unsigned short h) {
    return __uint_as_float(((unsigned int)h) << 16);
}
__device__ __forceinline__ int fkey(float f) {
    int b = __float_as_int(f);
    b ^= (b >> 31) & 0x7fffffff;   // order-preserving float -> int
    return b;
}
__device__ __forceinline__ float funkey(int b) {
    b ^= (b >> 31) & 0x7fffffff;
    return __int_as_float(b);
}

template <typename T> __device__ __forceinline__ T cvt_out(float v);
template <> __device__ __forceinline__ float  cvt_out<float>(float v)  { return v; }
template <> __device__ __forceinline__ __half cvt_out<__half>(float v) { return __float2half(v); }

// ---------------------------------------------------------------- CSR build
__global__ __launch_bounds__(256) void k_deg(const int* __restrict__ ei, int* __restrict__ deg) {
    int e = blockIdx.x * 256 + threadIdx.x;
    if (e >= N_EDGES) return;
    atomicAdd(&deg[ei[N_EDGES + e]], 1);
}

__global__ __launch_bounds__(256) void k_scan(const int* __restrict__ deg, int* __restrict__ rowptr) {
    __shared__ int part[256];
    int t = threadIdx.x;
    const int CH = 98;
    int base = t * CH;
    int s = 0;
    for (int i = 0; i < CH; ++i) {
        int idx = base + i;
        if (idx < N_NODES) s += deg[idx];
    }
    part[t] = s;
    __syncthreads();
    if (t == 0) {
        int run = 0;
        for (int i = 0; i < 256; ++i) { int v = part[i]; part[i] = run; run += v; }
    }
    __syncthreads();
    int run = part[t];
    for (int i = 0; i < CH; ++i) {
        int idx = base + i;
        if (idx < N_NODES) { rowptr[idx] = run; run += deg[idx]; }
    }
    if (N_NODES >= base && N_NODES < base + CH) rowptr[N_NODES] = run;
}

__global__ __launch_bounds__(256) void k_scatter(const int* __restrict__ ei,
                                                 const int* __restrict__ rowptr,
                                                 int* __restrict__ cursor,
                                                 int* __restrict__ csrc,
                                                 int* __restrict__ epos) {
    int e = blockIdx.x * 256 + threadIdx.x;
    if (e >= N_EDGES) return;
    int dst = ei[N_EDGES + e];
    int pos = atomicAdd(&cursor[dst], 1);
    int r = rowptr[dst] + pos;
    csrc[r] = ei[e];
    epos[e] = r;
}

// ---------------------------------------------------------------- weight prep
// W[K][1024] fp32 -> Wh/Wl [1024][K] bf16 (hi/lo split, transposed)
template <int K>
__global__ __launch_bounds__(256) void k_wsplit(const float* __restrict__ W,
                                                unsigned short* __restrict__ Wh,
                                                unsigned short* __restrict__ Wl) {
    int i = blockIdx.x * 256 + threadIdx.x;
    if (i >= K * 1024) return;
    int k = i >> 10, n = i & 1023;
    float w = W[i];
    unsigned short hi = f2bf(w);
    Wh[n * K + k] = hi;
    Wl[n * K + k] = f2bf(w - bf2f(hi));
}

// enc_w2 [32][1024] (j, i*32+o) -> W2t hi/lo [1024][32]: W2t[k=j*32+o][i]
__global__ __launch_bounds__(256) void k_w2perm(const float* __restrict__ w2,
                                                unsigned short* __restrict__ Wh,
                                                unsigned short* __restrict__ Wl) {
    int idx = blockIdx.x * 256 + threadIdx.x;   // k*32 + i
    if (idx >= 32 * 1024) return;
    int k = idx >> 5, i = idx & 31;
    float w = w2[(k >> 5) * 1024 + i * 32 + (k & 31)];
    unsigned short hi = f2bf(w);
    Wh[idx] = hi;
    Wl[idx] = f2bf(w - bf2f(hi));
}

// x [N][32] fp32 -> xh/xl bf16 + xb[n,o] = sum_i x[n,i]*b2[i*32+o]
__global__ __launch_bounds__(256) void k_xsplit(const float* __restrict__ x,
                                                const float* __restrict__ b2,
                                                unsigned short* __restrict__ xh,
                                                unsigned short* __restrict__ xl,
                                                float* __restrict__ xb) {
    int idx = blockIdx.x * 256 + threadIdx.x;
    if (idx >= N_NODES * 32) return;
    int n = idx >> 5, o = idx & 31;
    float v = x[idx];
    unsigned short hi = f2bf(v);
    xh[idx] = hi;
    xl[idx] = f2bf(v - bf2f(hi));
    float s = 0.f;
    for (int i = 0; i < 32; ++i) s += x[n * 32 + i] * b2[i * 32 + o];
    xb[idx] = s;
}

// ---------------------------------------------------------------- NNConv edge pass
__global__ __launch_bounds__(256) void k_msg(const float* __restrict__ ea,
                                             const float* __restrict__ w1,
                                             const float* __restrict__ b1,
                                             const int* __restrict__ ei,
                                             const __half* __restrict__ T,
                                             const float* __restrict__ xb,
                                             float* __restrict__ agg,
                                             float* __restrict__ cntf) {
    __shared__ float hb[8][IN_DIM];
    int t = threadIdx.x;
    int eg = t >> 5, o = t & 31;
    int e = blockIdx.x * 8 + eg;
    if (e < N_EDGES) {
        float a = b1[o];
        for (int k = 0; k < EDFD; ++k) a += ea[e * EDFD + k] * w1[k * 32 + o];
        hb[eg][o] = fmaxf(a, 0.f);
    }
    __syncthreads();
    if (e < N_EDGES) {
        int src = ei[e], dst = ei[N_EDGES + e];
        const __half* Tp = T + (size_t)src * 1024;
        float m = xb[src * IN_DIM + o];
        #pragma unroll
        for (int j = 0; j < IN_DIM; ++j) m += hb[eg][j] * __half2float(Tp[j * 32 + o]);
        atomicAdd(&agg[dst * IN_DIM + o], m);
        if (o == 0) atomicAdd(&cntf[dst], 1.f);
    }
}

// h0 = relu(agg/cnt + x@root_w + bias)  -> emit bf16 hi/lo
__global__ __launch_bounds__(256) void k_h0(const float* __restrict__ x,
                                            const float* __restrict__ root_w,
                                            const float* __restrict__ nn_bias,
                                            const float* __restrict__ agg,
                                            const float* __restrict__ cntf,
                                            unsigned short* __restrict__ ah,
                                            unsigned short* __restrict__ al) {
    int t = threadIdx.x;
    int ng = t >> 5, o = t & 31;
    int n = blockIdx.x * 8 + ng;
    if (n >= N_NODES) return;
    float s = nn_bias[o];
    for (int k = 0; k < IN_DIM; ++k) s += x[n * IN_DIM + k] * root_w[k * 32 + o];
    float c = fmaxf(cntf[n], 1.f);
    s += agg[n * IN_DIM + o] / c;
    float v = fmaxf(s, 0.f);
    unsigned short hi = f2bf(v);
    ah[n * IN_DIM + o] = hi;
    al[n * IN_DIM + o] = f2bf(v - bf2f(hi));
}

// ---------------------------------------------------------------- split-bf16 MFMA GEMM
template <int K, int MT, typename CT>
__global__ __launch_bounds__(256, 2) void k_mfmm(const unsigned short* __restrict__ Ah,
                                                 const unsigned short* __restrict__ Al,
                                                 const unsigned short* __restrict__ Wh,
                                                 const unsigned short* __restrict__ Wl,
                                                 CT* __restrict__ C) {
    constexpr int KS = K / 32;
    int wid = threadIdx.x >> 6, lane = threadIdx.x & 63;
    int lr = lane & 15;
    int lk = (lane >> 4) * 8;
    int n0 = blockIdx.x * 128 + wid * 32;

    short8v bh[KS][2], bl[KS][2];
    #pragma unroll
    for (int ks = 0; ks < KS; ++ks) {
        #pragma unroll
        for (int c = 0; c < 2; ++c) {
            size_t boff = (size_t)(n0 + c * 16 + lr) * K + ks * 32 + lk;
            bh[ks][c] = *(const short8v*)(Wh + boff);
            bl[ks][c] = *(const short8v*)(Wl + boff);
        }
    }

    int t0 = blockIdx.y * MT;
    int t1 = t0 + MT; if (t1 > M_PAD / 16) t1 = M_PAD / 16;
    for (int t = t0; t < t1; ++t) {
        int m0 = t * 16;
        const unsigned short* ar  = Ah + (size_t)(m0 + lr) * K + lk;
        const unsigned short* arl = Al + (size_t)(m0 + lr) * K + lk;
        short8v ah[KS], al[KS];
        #pragma unroll
        for (int ks = 0; ks < KS; ++ks) {
            ah[ks] = *(const short8v*)(ar + ks * 32);
            al[ks] = *(const short8v*)(arl + ks * 32);
        }
        f32x4 acc[2] = {{0.f,0.f,0.f,0.f},{0.f,0.f,0.f,0.f}};
        #pragma unroll
        for (int ks = 0; ks < KS; ++ks) {
            #pragma unroll
            for (int c = 0; c < 2; ++c) {
                acc[c] = __builtin_amdgcn_mfma_f32_16x16x32_bf16(ah[ks], bh[ks][c], acc[c], 0, 0, 0);
                acc[c] = __builtin_amdgcn_mfma_f32_16x16x32_bf16(ah[ks], bl[ks][c], acc[c], 0, 0, 0);
                acc[c] = __builtin_amdgcn_mfma_f32_16x16x32_bf16(al[ks], bh[ks][c], acc[c], 0, 0, 0);
            }
        }
        int rbase = (lane >> 4) * 4;
        #pragma unroll
        for (int c = 0; c < 2; ++c) {
            #pragma unroll
            for (int r = 0; r < 4; ++r)
                C[(size_t)(m0 + rbase + r) * 1024 + n0 + c * 16 + lr] = cvt_out<CT>(acc[c][r]);
        }
    }
}

// ---------------------------------------------------------------- GAT attention pieces
__global__ __launch_bounds__(256) void k_esed(const __half* __restrict__ hf,
                                              const float* __restrict__ asrc,
                                              const float* __restrict__ adst,
                                              float* __restrict__ es,
                                              float* __restrict__ ed) {
    int n = blockIdx.x;
    int h = threadIdx.x >> 6;
    int lane = threadIdx.x & 63;
    const __half* hp = hf + (size_t)n * 1024 + h * 256;
    float s = 0.f, d2 = 0.f;
    for (int d = lane; d < 256; d += 64) {
        float v = __half2float(hp[d]);
        s  += v * asrc[h * 256 + d];
        d2 += v * adst[h * 256 + d];
    }
    #pragma unroll
    for (int off = 32; off; off >>= 1) {
        s  += __shfl_down(s, off);
        d2 += __shfl_down(d2, off);
    }
    if (lane == 0) { es[n * 4 + h] = s; ed[n * 4 + h] = d2; }
}

// init mkey with self-loop value
__global__ __launch_bounds__(256) void k_minit(const float* __restrict__ es,
                                               const float* __restrict__ ed,
                                               int* __restrict__ mkey) {
    int i = blockIdx.x * 256 + threadIdx.x;
    if (i >= N_NODES * 4) return;
    mkey[i] = fkey(leaky(es[i] + ed[i]));
}

// edge-parallel segment max
__global__ __launch_bounds__(256) void k_mmax(const int* __restrict__ ei,
                                              const float* __restrict__ es,
                                              const float* __restrict__ ed,
                                              int* __restrict__ mkey) {
    int idx = blockIdx.x * 256 + threadIdx.x;   // e*4+h
    if (idx >= N_EDGES * 4) return;
    int e = idx >> 2, h = idx & 3;
    int src = ei[e], dst = ei[N_EDGES + e];
    atomicMax(&mkey[dst * 4 + h], fkey(leaky(es[src * 4 + h] + ed[dst * 4 + h])));
}

// edge-parallel weights: wv[CSR pos] = exp(v - m); den[dst,h] += w
__global__ __launch_bounds__(256) void k_watt(const int* __restrict__ ei,
                                              const int* __restrict__ epos,
                                              const float* __restrict__ es,
                                              const float* __restrict__ ed,
                                              const int* __restrict__ mkey,
                                              float* __restrict__ wv,
                                              float* __restrict__ den) {
    int idx = blockIdx.x * 256 + threadIdx.x;   // e*4+h
    if (idx >= N_EDGES * 4) return;
    int e = idx >> 2, h = idx & 3;
    int src = ei[e], dst = ei[N_EDGES + e];
    float v = leaky(es[src * 4 + h] + ed[dst * 4 + h]);
    float w = __expf(v - funkey(mkey[dst * 4 + h]));
    wv[(size_t)epos[e] * 4 + h] = w;
    atomicAdd(&den[dst * 4 + h], w);
}

// single-pass GAT aggregation: precomputed m/den/w, pure gather+FMA loop
template <bool EMIT_F32, bool EMIT_BF>
__global__ __launch_bounds__(256) void k_gat(const int* __restrict__ rowptr,
                                             const int* __restrict__ csrc,
                                             const float* __restrict__ es,
                                             const float* __restrict__ ed,
                                             const int* __restrict__ mkey,
                                             const float* __restrict__ denb,
                                             const float* __restrict__ wv,
                                             const __half* __restrict__ hf,
                                             const float* __restrict__ bias,
                                             float* __restrict__ hout,
                                             unsigned short* __restrict__ oh,
                                             unsigned short* __restrict__ ol) {
    __shared__ float sm[4][256];
    int dst = blockIdx.x;
    int h = threadIdx.x >> 6, lane = threadIdx.x & 63;
    int r0 = rowptr[dst], r1 = rowptr[dst + 1];
    float m = funkey(mkey[dst * 4 + h]);
    float vself = leaky(es[dst * 4 + h] + ed[dst * 4 + h]);
    float wself = __expf(vself - m);
    float den = denb[dst * 4 + h] + wself;
    const __half2* hp2 = (const __half2*)(hf + (size_t)dst * 1024 + h * 256);
    __half2 p0 = hp2[lane * 2], p1 = hp2[lane * 2 + 1];
    float2 f0 = __half22float2(p0), f1 = __half22float2(p1);
    float4 acc;
    acc.x = wself * f0.x; acc.y = wself * f0.y; acc.z = wself * f1.x; acc.w = wself * f1.y;
    for (int r = r0; r < r1; ++r) {
        int src = csrc[r];
        float w = wv[(size_t)r * 4 + h];
        const __half2* sp2 = (const __half2*)(hf + (size_t)src * 1024 + h * 256);
        __half2 s0 = sp2[lane * 2], s1 = sp2[lane * 2 + 1];
        float2 g0 = __half22float2(s0), g1 = __half22float2(s1);
        acc.x += w * g0.x; acc.y += w * g0.y; acc.z += w * g1.x; acc.w += w * g1.y;
    }
    float inv = 1.f / (den + 1e-16f);
    sm[h][lane * 4 + 0] = acc.x * inv;
    sm[h][lane * 4 + 1] = acc.y * inv;
    sm[h][lane * 4 + 2] = acc.z * inv;
    sm[h][lane * 4 + 3] = acc.w * inv;
    __syncthreads();
    int d = threadIdx.x;
    float s = 0.25f * (sm[0][d] + sm[1][d] + sm[2][d] + sm[3][d]) + bias[d];
    float v = fmaxf(s, 0.f);
    if (EMIT_F32) hout[(size_t)dst * 256 + d] = v;
    if (EMIT_BF) {
        unsigned short hi = f2bf(v);
        oh[(size_t)dst * 256 + d] = hi;
        ol[(size_t)dst * 256 + d] = f2bf(v - bf2f(hi));
    }
}

// ---------------------------------------------------------------- heads
__global__ __launch_bounds__(256) void k_wire(const int* __restrict__ wm,
                                              const float* __restrict__ h2,
                                              const float* __restrict__ ww,
                                              const float* __restrict__ wb,
                                              float* __restrict__ out) {
    int k = blockIdx.x * 4 + (threadIdx.x >> 6);
    int lane = threadIdx.x & 63;
    if (k >= KWIRE) return;
    int n = wm[k];
    float s = 0.f;
    for (int d = lane; d < 256; d += 64) s += h2[(size_t)n * 256 + d] * ww[d];
    #pragma unroll
    for (int off = 32; off; off >>= 1) s += __shfl_down(s, off);
    if (lane == 0) out[k] = s + wb[0];
}

__global__ __launch_bounds__(256) void k_pool(const float* __restrict__ h2,
                                              const int* __restrict__ batch,
                                              float* __restrict__ pooled,
                                              float* __restrict__ gcnt) {
    int n0 = blockIdx.x * POOL_NB;
    int n1 = n0 + POOL_NB; if (n1 > N_NODES) n1 = N_NODES;
    int d = threadIdx.x;
    int cur = batch[n0];
    float acc = 0.f, cnt = 0.f;
    for (int n = n0; n < n1; ++n) {
        int g = batch[n];
        if (g != cur) {
            atomicAdd(&pooled[cur * 256 + d], acc);
            if (d == 0) atomicAdd(&gcnt[cur], cnt);
            acc = 0.f; cnt = 0.f; cur = g;
        }
        acc += h2[(size_t)n * 256 + d];
        cnt += 1.f;
    }
    atomicAdd(&pooled[cur * 256 + d], acc);
    if (d == 0) atomicAdd(&gcnt[cur], cnt);
}

__global__ __launch_bounds__(256) void k_act(const float* __restrict__ pooled,
                                             const float* __restrict__ gcnt,
                                             const float* __restrict__ aw,
                                             const float* __restrict__ ab,
                                             float* __restrict__ out) {
    int u = blockIdx.x * 4 + (threadIdx.x >> 6);
    int lane = threadIdx.x & 63;
    if (u >= NGRAPH * NACT) return;
    int g = u >> 4, a = u & 15;
    float c = fmaxf(gcnt[g], 1.f);
    float s = 0.f;
    for (int d = lane; d < 256; d += 64) s += pooled[g * 256 + d] * aw[d * 16 + a];
    #pragma unroll
    for (int off = 32; off; off >>= 1) s += __shfl_down(s, off);
    if (lane == 0) out[KWIRE + u] = s / c + ab[a];
}

// ---------------------------------------------------------------- launch
extern "C" void kernel_launch(void* const* d_in, const int* in_sizes, int n_in,
                              void* d_out, int out_size, void* d_ws, size_t ws_size,
                              hipStream_t stream) {
    const float* x        = (const float*)d_in[0];
    const float* edge_attr= (const float*)d_in[1];
    const int*   wire_mask= (const int*)d_in[2];
    const int*   edge_idx = (const int*)d_in[3];
    const int*   batch    = (const int*)d_in[4];
    const float* enc_w1   = (const float*)d_in[5];
    const float* enc_b1   = (const float*)d_in[6];
    const float* enc_w2   = (const float*)d_in[7];
    const float* enc_b2   = (const float*)d_in[8];
    const float* root_w   = (const float*)d_in[9];
    const float* nn_bias  = (const float*)d_in[10];
    const float* gat1_w   = (const float*)d_in[11];
    const float* gat1_asrc= (const float*)d_in[12];
    const float* gat1_adst= (const float*)d_in[13];
    const float* gat1_b   = (const float*)d_in[14];
    const float* gat2_w   = (const float*)d_in[15];
    const float* gat2_asrc= (const float*)d_in[16];
    const float* gat2_adst= (const float*)d_in[17];
    const float* gat2_b   = (const float*)d_in[18];
    const float* wire_w   = (const float*)d_in[19];
    const float* wire_b   = (const float*)d_in[20];
    const float* act_w    = (const float*)d_in[21];
    const float* act_b    = (const float*)d_in[22];
    float* out = (float*)d_out;

    float* ws = (float*)d_ws;
    size_t off = 0;
    __half* T16    = (__half*)(ws + off); off += (size_t)M_PAD * 1024 / 2;   // 51.2 MB
    __half* hfrag  = (__half*)(ws + off); off += (size_t)M_PAD * 1024 / 2;   // 51.2 MB
    float* xb     = ws + off; off += 800000;
    float* agg    = ws + off; off += 800000;
    float* cntf   = ws + off; off += 25600;
    float* esb    = ws + off; off += 100000;
    float* edb    = ws + off; off += 100000;
    float* h2     = ws + off; off += 6400000;
    float* pooled = ws + off; off += NGRAPH * 256;
    float* gcnt   = ws + off; off += NGRAPH;
    int* deg      = (int*)(ws + off); off += 25600;
    int* rowptr   = (int*)(ws + off); off += 25600;
    int* cursor   = (int*)(ws + off); off += 25600;
    int* csrc     = (int*)(ws + off); off += N_EDGES;
    int* epos     = (int*)(ws + off); off += N_EDGES;
    int* mkey     = (int*)(ws + off); off += 100000;
    float* den    = ws + off; off += 100000;
    float* wv     = ws + off; off += (size_t)N_EDGES * 4;    // 4.8 MB
    unsigned short* w1h = (unsigned short*)(ws + off); off += 16384;
    unsigned short* w1l = (unsigned short*)(ws + off); off += 16384;
    unsigned short* w2h = (unsigned short*)(ws + off); off += 131072;
    unsigned short* w2l = (unsigned short*)(ws + off); off += 131072;
    unsigned short* wth = (unsigned short*)(ws + off); off += 16384;
    unsigned short* wtl = (unsigned short*)(ws + off); off += 16384;
    unsigned short* xh  = (unsigned short*)(ws + off); off += (size_t)M_PAD * 32 / 2;
    unsigned short* xl  = (unsigned short*)(ws + off); off += (size_t)M_PAD * 32 / 2;
    unsigned short* h0h = (unsigned short*)(ws + off); off += (size_t)M_PAD * 32 / 2;
    unsigned short* h0l = (unsigned short*)(ws + off); off += (size_t)M_PAD * 32 / 2;
    unsigned short* h1h = (unsigned short*)(ws + off); off += (size_t)M_PAD * 256 / 2;
    unsigned short* h1l = (unsigned short*)(ws + off); off += (size_t)M_PAD * 256 / 2;

    const int EH = N_EDGES * 4;

    // ---- CSR build (by dst) ----
    hipMemsetAsync(deg, 0, 25600 * sizeof(int), stream);
    hipMemsetAsync(cursor, 0, 25600 * sizeof(int), stream);
    k_deg<<<(N_EDGES + 255) / 256, 256, 0, stream>>>(edge_idx, deg);
    k_scan<<<1, 256, 0, stream>>>(deg, rowptr);
    k_scatter<<<(N_EDGES + 255) / 256, 256, 0, stream>>>(edge_idx, rowptr, cursor, csrc, epos);

    // ---- weight prep ----
    k_wsplit<IN_DIM><<<(IN_DIM * 1024 + 255) / 256, 256, 0, stream>>>(gat1_w, w1h, w1l);
    k_wsplit<HIDD><<<(HIDD * 1024 + 255) / 256, 256, 0, stream>>>(gat2_w, w2h, w2l);
    k_w2perm<<<(32 * 1024 + 255) / 256, 256, 0, stream>>>(enc_w2, wth, wtl);
    k_xsplit<<<(N_NODES * 32 + 255) / 256, 256, 0, stream>>>(x, enc_b2, xh, xl, xb);

    // ---- NNConv ----
    hipMemsetAsync(agg, 0, (800000 + 25600) * sizeof(float), stream);
    {
        dim3 g(8, (M_PAD / 16 + 24) / 25);
        k_mfmm<IN_DIM, 25, __half><<<g, 256, 0, stream>>>(xh, xl, wth, wtl, T16);
    }
    k_msg<<<N_EDGES / 8, 256, 0, stream>>>(edge_attr, enc_w1, enc_b1, edge_idx, T16, xb, agg, cntf);
    k_h0<<<N_NODES / 8, 256, 0, stream>>>(x, root_w, nn_bias, agg, cntf, h0h, h0l);

    // ---- GAT layer 1 ----
    {
        dim3 g(8, (M_PAD / 16 + 24) / 25);
        k_mfmm<IN_DIM, 25, __half><<<g, 256, 0, stream>>>(h0h, h0l, w1h, w1l, hfrag);
    }
    k_esed<<<N_NODES, 256, 0, stream>>>(hfrag, gat1_asrc, gat1_adst, esb, edb);
    hipMemsetAsync(den, 0, 100000 * sizeof(float), stream);
    k_minit<<<(N_NODES * 4 + 255) / 256, 256, 0, stream>>>(esb, edb, mkey);
    k_mmax<<<(EH + 255) / 256, 256, 0, stream>>>(edge_idx, esb, edb, mkey);
    k_watt<<<(EH + 255) / 256, 256, 0, stream>>>(edge_idx, epos, esb, edb, mkey, wv, den);
    k_gat<false, true><<<N_NODES, 256, 0, stream>>>(rowptr, csrc, esb, edb, mkey, den, wv,
                                                    hfrag, gat1_b, nullptr, h1h, h1l);

    // ---- GAT layer 2 ----
    {
        dim3 g(8, (M_PAD / 16 + 24) / 25);
        k_mfmm<HIDD, 25, __half><<<g, 256, 0, stream>>>(h1h, h1l, w2h, w2l, hfrag);
    }
    k_esed<<<N_NODES, 256, 0, stream>>>(hfrag, gat2_asrc, gat2_adst, esb, edb);
    hipMemsetAsync(den, 0, 100000 * sizeof(float), stream);
    k_minit<<<(N_NODES * 4 + 255) / 256, 256, 0, stream>>>(esb, edb, mkey);
    k_mmax<<<(EH + 255) / 256, 256, 0, stream>>>(edge_idx, esb, edb, mkey);
    k_watt<<<(EH + 255) / 256, 256, 0, stream>>>(edge_idx, epos, esb, edb, mkey, wv, den);
    k_gat<true, false><<<N_NODES, 256, 0, stream>>>(rowptr, csrc, esb, edb, mkey, den, wv,
                                                    hfrag, gat2_b, h2, nullptr, nullptr);

    // ---- heads ----
    k_wire<<<KWIRE / 4, 256, 0, stream>>>(wire_mask, h2, wire_w, wire_b, out);
    hipMemsetAsync(pooled, 0, (NGRAPH * 256 + NGRAPH) * sizeof(float), stream);
    k_pool<<<(N_NODES + POOL_NB - 1) / POOL_NB, 256, 0, stream>>>(h2, batch, pooled, gcnt);
    k_act<<<NGRAPH * NACT / 4, 256, 0, stream>>>(pooled, gcnt, act_w, act_b, out);
}

// Round 9
// 679.959 us; speedup vs baseline: 1.0364x; 1.0364x over previous
//
#include <hip/hip_runtime.h>
#include <hip/hip_bf16.h>
#include <hip/hip_fp16.h>

#define N_NODES 25000
#define M_PAD   25024            // multiple of 16 (1564 tiles)
#define N_TILES 1564
#define N_EDGES 300000
#define IN_DIM  32
#define EDFD    16
#define HIDD    256
#define HEADS   4
#define NACT    16
#define NGRAPH  64
#define KWIRE   1024
#define POOL_NB 64

typedef __attribute__((ext_vector_type(8))) short short8v;
typedef __attribute__((ext_vector_type(4))) float f32x4;

// ---------------------------------------------------------------- helpers
__device__ __forceinline__ float leaky(float v) { return v > 0.f ? v : 0.2f * v; }
__device__ __forceinline__ unsigned short f2bf(float f) {
    unsigned int u = __float_as_uint(f);
    u += 0x7fff + ((u >> 16) & 1);
    return (unsigned short)(u >> 16);
}
__device__ __forceinline__ float bf2f(unsigned short h) {
    return __uint_as_float(((unsigned int)h) << 16);
}
__device__ __forceinline__ int fkey(float f) {
    int b = __float_as_int(f);
    b ^= (b >> 31) & 0x7fffffff;
    return b;
}
__device__ __forceinline__ float funkey(int b) {
    b ^= (b >> 31) & 0x7fffffff;
    return __int_as_float(b);
}

// ---------------------------------------------------------------- CSR build
__global__ __launch_bounds__(256) void k_deg(const int* __restrict__ ei, int* __restrict__ deg) {
    int e = blockIdx.x * 256 + threadIdx.x;
    if (e >= N_EDGES) return;
    atomicAdd(&deg[ei[N_EDGES + e]], 1);
}

__global__ __launch_bounds__(256) void k_scan(const int* __restrict__ deg, int* __restrict__ rowptr) {
    __shared__ int part[256];
    int t = threadIdx.x;
    const int CH = 98;
    int base = t * CH;
    int s = 0;
    for (int i = 0; i < CH; ++i) {
        int idx = base + i;
        if (idx < N_NODES) s += deg[idx];
    }
    part[t] = s;
    __syncthreads();
    if (t == 0) {
        int run = 0;
        for (int i = 0; i < 256; ++i) { int v = part[i]; part[i] = run; run += v; }
    }
    __syncthreads();
    int run = part[t];
    for (int i = 0; i < CH; ++i) {
        int idx = base + i;
        if (idx < N_NODES) { rowptr[idx] = run; run += deg[idx]; }
    }
    if (N_NODES >= base && N_NODES < base + CH) rowptr[N_NODES] = run;
}

__global__ __launch_bounds__(256) void k_scatter(const int* __restrict__ ei,
                                                 const int* __restrict__ rowptr,
                                                 int* __restrict__ cursor,
                                                 int* __restrict__ csrc,
                                                 int* __restrict__ epos) {
    int e = blockIdx.x * 256 + threadIdx.x;
    if (e >= N_EDGES) return;
    int dst = ei[N_EDGES + e];
    int pos = atomicAdd(&cursor[dst], 1);
    int r = rowptr[dst] + pos;
    csrc[r] = ei[e];
    epos[e] = r;
}

// ---------------------------------------------------------------- weight prep
template <int K>
__global__ __launch_bounds__(256) void k_wsplit(const float* __restrict__ W,
                                                unsigned short* __restrict__ Wh,
                                                unsigned short* __restrict__ Wl) {
    int i = blockIdx.x * 256 + threadIdx.x;
    if (i >= K * 1024) return;
    int k = i >> 10, n = i & 1023;
    float w = W[i];
    unsigned short hi = f2bf(w);
    Wh[n * K + k] = hi;
    Wl[n * K + k] = f2bf(w - bf2f(hi));
}

__global__ __launch_bounds__(256) void k_w2perm(const float* __restrict__ w2,
                                                unsigned short* __restrict__ Wh,
                                                unsigned short* __restrict__ Wl) {
    int idx = blockIdx.x * 256 + threadIdx.x;   // k*32 + i
    if (idx >= 32 * 1024) return;
    int k = idx >> 5, i = idx & 31;
    float w = w2[(k >> 5) * 1024 + i * 32 + (k & 31)];
    unsigned short hi = f2bf(w);
    Wh[idx] = hi;
    Wl[idx] = f2bf(w - bf2f(hi));
}

__global__ __launch_bounds__(256) void k_xsplit(const float* __restrict__ x,
                                                const float* __restrict__ b2,
                                                unsigned short* __restrict__ xh,
                                                unsigned short* __restrict__ xl,
                                                float* __restrict__ xb) {
    int idx = blockIdx.x * 256 + threadIdx.x;
    if (idx >= N_NODES * 32) return;
    int n = idx >> 5, o = idx & 31;
    float v = x[idx];
    unsigned short hi = f2bf(v);
    xh[idx] = hi;
    xl[idx] = f2bf(v - bf2f(hi));
    float s = 0.f;
    for (int i = 0; i < 32; ++i) s += x[n * 32 + i] * b2[i * 32 + o];
    xb[idx] = s;
}

// ---------------------------------------------------------------- NNConv edge pass
__global__ __launch_bounds__(256) void k_msg(const float* __restrict__ ea,
                                             const float* __restrict__ w1,
                                             const float* __restrict__ b1,
                                             const int* __restrict__ ei,
                                             const __half* __restrict__ T,
                                             const float* __restrict__ xb,
                                             float* __restrict__ agg,
                                             float* __restrict__ cntf) {
    __shared__ float hb[8][IN_DIM];
    int t = threadIdx.x;
    int eg = t >> 5, o = t & 31;
    int e = blockIdx.x * 8 + eg;
    if (e < N_EDGES) {
        float a = b1[o];
        for (int k = 0; k < EDFD; ++k) a += ea[e * EDFD + k] * w1[k * 32 + o];
        hb[eg][o] = fmaxf(a, 0.f);
    }
    __syncthreads();
    if (e < N_EDGES) {
        int src = ei[e], dst = ei[N_EDGES + e];
        const __half* Tp = T + (size_t)src * 1024;
        float m = xb[src * IN_DIM + o];
        #pragma unroll
        for (int j = 0; j < IN_DIM; ++j) m += hb[eg][j] * __half2float(Tp[j * 32 + o]);
        atomicAdd(&agg[dst * IN_DIM + o], m);
        if (o == 0) atomicAdd(&cntf[dst], 1.f);
    }
}

__global__ __launch_bounds__(256) void k_h0(const float* __restrict__ x,
                                            const float* __restrict__ root_w,
                                            const float* __restrict__ nn_bias,
                                            const float* __restrict__ agg,
                                            const float* __restrict__ cntf,
                                            unsigned short* __restrict__ ah,
                                            unsigned short* __restrict__ al) {
    int t = threadIdx.x;
    int ng = t >> 5, o = t & 31;
    int n = blockIdx.x * 8 + ng;
    if (n >= N_NODES) return;
    float s = nn_bias[o];
    for (int k = 0; k < IN_DIM; ++k) s += x[n * IN_DIM + k] * root_w[k * 32 + o];
    float c = fmaxf(cntf[n], 1.f);
    s += agg[n * IN_DIM + o] / c;
    float v = fmaxf(s, 0.f);
    unsigned short hi = f2bf(v);
    ah[n * IN_DIM + o] = hi;
    al[n * IN_DIM + o] = f2bf(v - bf2f(hi));
}

// ---------------------------------------------------------------- tiled split-bf16 MFMA GEMM
// C[M_PAD,1024](fp16) = A[M_PAD,K] @ W[K,1024]
// Block: 32-col strip (x), 4 waves x TPW row-tiles (y). B staged in LDS (XOR swizzle),
// C staged per-wave in LDS -> 16B coalesced global stores (no partial-line RMW).
template <int K>
__global__ __launch_bounds__(256) void k_gemm(const unsigned short* __restrict__ Ah,
                                              const unsigned short* __restrict__ Al,
                                              const unsigned short* __restrict__ Wh,
                                              const unsigned short* __restrict__ Wl,
                                              __half* __restrict__ C) {
    constexpr int KS = K / 32;
    constexpr int SH = (K == 256) ? 9 : 6;       // log2(K*2) : bytes per LDS col
    constexpr int TPW = 4;                       // row-tiles per wave
    __shared__ unsigned short bsh[32 * K];
    __shared__ unsigned short bsl[32 * K];
    __shared__ __half cst[4][16 * 32];
    int t = threadIdx.x, wid = t >> 6, lane = t & 63;
    int lr = lane & 15, lk = (lane >> 4) * 8;
    int n0 = blockIdx.x * 32;

    // stage B hi/lo, swizzled: byte ^= ((col&7)<<4)
    {
        const char* srcH = (const char*)(Wh + (size_t)n0 * K);
        const char* srcL = (const char*)(Wl + (size_t)n0 * K);
        for (int i = t * 16; i < 32 * K * 2; i += 256 * 16) {
            int sb = i ^ (((i >> SH) & 7) << 4);
            *(float4*)((char*)bsh + sb) = *(const float4*)(srcH + i);
            *(float4*)((char*)bsl + sb) = *(const float4*)(srcL + i);
        }
    }
    __syncthreads();

    const int swz = (lr & 7) << 4;
    const int base0 = ((0 * 16 + lr) << SH) + lk * 2;
    const int base1 = ((1 * 16 + lr) << SH) + lk * 2;

    int tb = (blockIdx.y * 4 + wid) * TPW;
    for (int pp = 0; pp < TPW; pp += 2) {
        int tA = tb + pp;
        if (tA >= N_TILES) break;
        int tB = tA + 1;                          // N_TILES even, tb multiple of 4 -> pair valid
        int mA = tA * 16, mB = tB * 16;
        const unsigned short* pAh = Ah + (size_t)(mA + lr) * K + lk;
        const unsigned short* pAl = Al + (size_t)(mA + lr) * K + lk;
        const unsigned short* pBh = Ah + (size_t)(mB + lr) * K + lk;
        const unsigned short* pBl = Al + (size_t)(mB + lr) * K + lk;

        f32x4 acc[2][2];
        #pragma unroll
        for (int i = 0; i < 2; ++i)
            #pragma unroll
            for (int c = 0; c < 2; ++c)
                acc[i][c] = (f32x4){0.f, 0.f, 0.f, 0.f};

        #pragma unroll
        for (int ks = 0; ks < KS; ++ks) {
            short8v aAh = *(const short8v*)(pAh + ks * 32);
            short8v aAl = *(const short8v*)(pAl + ks * 32);
            short8v aBh = *(const short8v*)(pBh + ks * 32);
            short8v aBl = *(const short8v*)(pBl + ks * 32);
            short8v bh0 = *(const short8v*)((const char*)bsh + ((base0 + ks * 64) ^ swz));
            short8v bl0 = *(const short8v*)((const char*)bsl + ((base0 + ks * 64) ^ swz));
            short8v bh1 = *(const short8v*)((const char*)bsh + ((base1 + ks * 64) ^ swz));
            short8v bl1 = *(const short8v*)((const char*)bsl + ((base1 + ks * 64) ^ swz));
            acc[0][0] = __builtin_amdgcn_mfma_f32_16x16x32_bf16(aAh, bh0, acc[0][0], 0, 0, 0);
            acc[0][0] = __builtin_amdgcn_mfma_f32_16x16x32_bf16(aAl, bh0, acc[0][0], 0, 0, 0);
            acc[0][0] = __builtin_amdgcn_mfma_f32_16x16x32_bf16(aAh, bl0, acc[0][0], 0, 0, 0);
            acc[0][1] = __builtin_amdgcn_mfma_f32_16x16x32_bf16(aAh, bh1, acc[0][1], 0, 0, 0);
            acc[0][1] = __builtin_amdgcn_mfma_f32_16x16x32_bf16(aAl, bh1, acc[0][1], 0, 0, 0);
            acc[0][1] = __builtin_amdgcn_mfma_f32_16x16x32_bf16(aAh, bl1, acc[0][1], 0, 0, 0);
            acc[1][0] = __builtin_amdgcn_mfma_f32_16x16x32_bf16(aBh, bh0, acc[1][0], 0, 0, 0);
            acc[1][0] = __builtin_amdgcn_mfma_f32_16x16x32_bf16(aBl, bh0, acc[1][0], 0, 0, 0);
            acc[1][0] = __builtin_amdgcn_mfma_f32_16x16x32_bf16(aBh, bl0, acc[1][0], 0, 0, 0);
            acc[1][1] = __builtin_amdgcn_mfma_f32_16x16x32_bf16(aBh, bh1, acc[1][1], 0, 0, 0);
            acc[1][1] = __builtin_amdgcn_mfma_f32_16x16x32_bf16(aBl, bh1, acc[1][1], 0, 0, 0);
            acc[1][1] = __builtin_amdgcn_mfma_f32_16x16x32_bf16(aBh, bl1, acc[1][1], 0, 0, 0);
        }

        int rbase = (lane >> 4) * 4;
        int row = lane >> 2, ch = lane & 3;
        #pragma unroll
        for (int ti = 0; ti < 2; ++ti) {
            #pragma unroll
            for (int c = 0; c < 2; ++c)
                #pragma unroll
                for (int r = 0; r < 4; ++r)
                    cst[wid][(rbase + r) * 32 + c * 16 + lr] = __float2half(acc[ti][c][r]);
            // wave-private staging: compiler inserts lgkmcnt waits (same LDS object)
            float4 v = *(const float4*)((const char*)&cst[wid][0] + row * 64 + ch * 16);
            int m0 = ti ? mB : mA;
            *(float4*)((char*)C + ((size_t)(m0 + row) * 1024 + n0) * 2 + ch * 16) = v;
        }
    }
}

// ---------------------------------------------------------------- GAT attention pieces
__global__ __launch_bounds__(256) void k_esed(const __half* __restrict__ hf,
                                              const float* __restrict__ asrc,
                                              const float* __restrict__ adst,
                                              float* __restrict__ es,
                                              float* __restrict__ ed) {
    int n = blockIdx.x;
    int h = threadIdx.x >> 6;
    int lane = threadIdx.x & 63;
    const __half* hp = hf + (size_t)n * 1024 + h * 256;
    float s = 0.f, d2 = 0.f;
    for (int d = lane; d < 256; d += 64) {
        float v = __half2float(hp[d]);
        s  += v * asrc[h * 256 + d];
        d2 += v * adst[h * 256 + d];
    }
    #pragma unroll
    for (int off = 32; off; off >>= 1) {
        s  += __shfl_down(s, off);
        d2 += __shfl_down(d2, off);
    }
    if (lane == 0) { es[n * 4 + h] = s; ed[n * 4 + h] = d2; }
}

__global__ __launch_bounds__(256) void k_minit(const float* __restrict__ es,
                                               const float* __restrict__ ed,
                                               int* __restrict__ mkey) {
    int i = blockIdx.x * 256 + threadIdx.x;
    if (i >= N_NODES * 4) return;
    mkey[i] = fkey(leaky(es[i] + ed[i]));
}

__global__ __launch_bounds__(256) void k_mmax(const int* __restrict__ ei,
                                              const float* __restrict__ es,
                                              const float* __restrict__ ed,
                                              int* __restrict__ mkey) {
    int idx = blockIdx.x * 256 + threadIdx.x;
    if (idx >= N_EDGES * 4) return;
    int e = idx >> 2, h = idx & 3;
    int src = ei[e], dst = ei[N_EDGES + e];
    atomicMax(&mkey[dst * 4 + h], fkey(leaky(es[src * 4 + h] + ed[dst * 4 + h])));
}

__global__ __launch_bounds__(256) void k_watt(const int* __restrict__ ei,
                                              const int* __restrict__ epos,
                                              const float* __restrict__ es,
                                              const float* __restrict__ ed,
                                              const int* __restrict__ mkey,
                                              float* __restrict__ wv,
                                              float* __restrict__ den) {
    int idx = blockIdx.x * 256 + threadIdx.x;
    if (idx >= N_EDGES * 4) return;
    int e = idx >> 2, h = idx & 3;
    int src = ei[e], dst = ei[N_EDGES + e];
    float v = leaky(es[src * 4 + h] + ed[dst * 4 + h]);
    float w = __expf(v - funkey(mkey[dst * 4 + h]));
    wv[(size_t)epos[e] * 4 + h] = w;
    atomicAdd(&den[dst * 4 + h], w);
}

// single-pass GAT aggregation with 8-way batched gathers
template <bool EMIT_F32, bool EMIT_BF>
__global__ __launch_bounds__(256) void k_gat(const int* __restrict__ rowptr,
                                             const int* __restrict__ csrc,
                                             const float* __restrict__ es,
                                             const float* __restrict__ ed,
                                             const int* __restrict__ mkey,
                                             const float* __restrict__ denb,
                                             const float* __restrict__ wv,
                                             const __half* __restrict__ hf,
                                             const float* __restrict__ bias,
                                             float* __restrict__ hout,
                                             unsigned short* __restrict__ oh,
                                             unsigned short* __restrict__ ol) {
    __shared__ float sm[4][256];
    int dst = blockIdx.x;
    int h = threadIdx.x >> 6, lane = threadIdx.x & 63;
    int r0 = rowptr[dst], r1 = rowptr[dst + 1];
    float m = funkey(mkey[dst * 4 + h]);
    float vself = leaky(es[dst * 4 + h] + ed[dst * 4 + h]);
    float wself = __expf(vself - m);
    float den = denb[dst * 4 + h] + wself;

    float2 q = *(const float2*)(hf + (size_t)dst * 1024 + h * 256 + lane * 4);
    const __half2* hq = (const __half2*)&q;
    float2 f0 = __half22float2(hq[0]), f1 = __half22float2(hq[1]);
    float4 acc;
    acc.x = wself * f0.x; acc.y = wself * f0.y; acc.z = wself * f1.x; acc.w = wself * f1.y;

    for (int r = r0; r < r1; r += 8) {
        int cnt = r1 - r; if (cnt > 8) cnt = 8;
        int sv[8]; float wvv[8];
        #pragma unroll
        for (int i = 0; i < 8; ++i) {
            sv[i]  = (i < cnt) ? csrc[r + i] : dst;
            wvv[i] = (i < cnt) ? wv[(size_t)(r + i) * 4 + h] : 0.f;
        }
        #pragma unroll
        for (int i = 0; i < 8; ++i) {
            float2 g = *(const float2*)(hf + (size_t)sv[i] * 1024 + h * 256 + lane * 4);
            const __half2* gq = (const __half2*)&g;
            float2 g0 = __half22float2(gq[0]), g1 = __half22float2(gq[1]);
            float w = wvv[i];
            acc.x += w * g0.x; acc.y += w * g0.y; acc.z += w * g1.x; acc.w += w * g1.y;
        }
    }
    float inv = 1.f / (den + 1e-16f);
    sm[h][lane * 4 + 0] = acc.x * inv;
    sm[h][lane * 4 + 1] = acc.y * inv;
    sm[h][lane * 4 + 2] = acc.z * inv;
    sm[h][lane * 4 + 3] = acc.w * inv;
    __syncthreads();
    int d = threadIdx.x;
    float s = 0.25f * (sm[0][d] + sm[1][d] + sm[2][d] + sm[3][d]) + bias[d];
    float v = fmaxf(s, 0.f);
    if (EMIT_F32) hout[(size_t)dst * 256 + d] = v;
    if (EMIT_BF) {
        unsigned short hi = f2bf(v);
        oh[(size_t)dst * 256 + d] = hi;
        ol[(size_t)dst * 256 + d] = f2bf(v - bf2f(hi));
    }
}

// ---------------------------------------------------------------- heads
__global__ __launch_bounds__(256) void k_wire(const int* __restrict__ wm,
                                              const float* __restrict__ h2,
                                              const float* __restrict__ ww,
                                              const float* __restrict__ wb,
                                              float* __restrict__ out) {
    int k = blockIdx.x * 4 + (threadIdx.x >> 6);
    int lane = threadIdx.x & 63;
    if (k >= KWIRE) return;
    int n = wm[k];
    float s = 0.f;
    for (int d = lane; d < 256; d += 64) s += h2[(size_t)n * 256 + d] * ww[d];
    #pragma unroll
    for (int off = 32; off; off >>= 1) s += __shfl_down(s, off);
    if (lane == 0) out[k] = s + wb[0];
}

__global__ __launch_bounds__(256) void k_pool(const float* __restrict__ h2,
                                              const int* __restrict__ batch,
                                              float* __restrict__ pooled,
                                              float* __restrict__ gcnt) {
    int n0 = blockIdx.x * POOL_NB;
    int n1 = n0 + POOL_NB; if (n1 > N_NODES) n1 = N_NODES;
    int d = threadIdx.x;
    int cur = batch[n0];
    float acc = 0.f, cnt = 0.f;
    for (int n = n0; n < n1; ++n) {
        int g = batch[n];
        if (g != cur) {
            atomicAdd(&pooled[cur * 256 + d], acc);
            if (d == 0) atomicAdd(&gcnt[cur], cnt);
            acc = 0.f; cnt = 0.f; cur = g;
        }
        acc += h2[(size_t)n * 256 + d];
        cnt += 1.f;
    }
    atomicAdd(&pooled[cur * 256 + d], acc);
    if (d == 0) atomicAdd(&gcnt[cur], cnt);
}

__global__ __launch_bounds__(256) void k_act(const float* __restrict__ pooled,
                                             const float* __restrict__ gcnt,
                                             const float* __restrict__ aw,
                                             const float* __restrict__ ab,
                                             float* __restrict__ out) {
    int u = blockIdx.x * 4 + (threadIdx.x >> 6);
    int lane = threadIdx.x & 63;
    if (u >= NGRAPH * NACT) return;
    int g = u >> 4, a = u & 15;
    float c = fmaxf(gcnt[g], 1.f);
    float s = 0.f;
    for (int d = lane; d < 256; d += 64) s += pooled[g * 256 + d] * aw[d * 16 + a];
    #pragma unroll
    for (int off = 32; off; off >>= 1) s += __shfl_down(s, off);
    if (lane == 0) out[KWIRE + u] = s / c + ab[a];
}

// ---------------------------------------------------------------- launch
extern "C" void kernel_launch(void* const* d_in, const int* in_sizes, int n_in,
                              void* d_out, int out_size, void* d_ws, size_t ws_size,
                              hipStream_t stream) {
    const float* x        = (const float*)d_in[0];
    const float* edge_attr= (const float*)d_in[1];
    const int*   wire_mask= (const int*)d_in[2];
    const int*   edge_idx = (const int*)d_in[3];
    const int*   batch    = (const int*)d_in[4];
    const float* enc_w1   = (const float*)d_in[5];
    const float* enc_b1   = (const float*)d_in[6];
    const float* enc_w2   = (const float*)d_in[7];
    const float* enc_b2   = (const float*)d_in[8];
    const float* root_w   = (const float*)d_in[9];
    const float* nn_bias  = (const float*)d_in[10];
    const float* gat1_w   = (const float*)d_in[11];
    const float* gat1_asrc= (const float*)d_in[12];
    const float* gat1_adst= (const float*)d_in[13];
    const float* gat1_b   = (const float*)d_in[14];
    const float* gat2_w   = (const float*)d_in[15];
    const float* gat2_asrc= (const float*)d_in[16];
    const float* gat2_adst= (const float*)d_in[17];
    const float* gat2_b   = (const float*)d_in[18];
    const float* wire_w   = (const float*)d_in[19];
    const float* wire_b   = (const float*)d_in[20];
    const float* act_w    = (const float*)d_in[21];
    const float* act_b    = (const float*)d_in[22];
    float* out = (float*)d_out;

    float* ws = (float*)d_ws;
    size_t off = 0;
    __half* T16    = (__half*)(ws + off); off += (size_t)M_PAD * 1024 / 2;
    __half* hfrag  = (__half*)(ws + off); off += (size_t)M_PAD * 1024 / 2;
    float* xb     = ws + off; off += 800000;
    float* agg    = ws + off; off += 800000;
    float* cntf   = ws + off; off += 25600;
    float* esb    = ws + off; off += 100000;
    float* edb    = ws + off; off += 100000;
    float* h2     = ws + off; off += 6400000;
    float* pooled = ws + off; off += NGRAPH * 256;
    float* gcnt   = ws + off; off += NGRAPH;
    int* deg      = (int*)(ws + off); off += 25600;
    int* rowptr   = (int*)(ws + off); off += 25600;
    int* cursor   = (int*)(ws + off); off += 25600;
    int* csrc     = (int*)(ws + off); off += N_EDGES;
    int* epos     = (int*)(ws + off); off += N_EDGES;
    int* mkey     = (int*)(ws + off); off += 100000;
    float* den    = ws + off; off += 100000;
    float* wv     = ws + off; off += (size_t)N_EDGES * 4;
    unsigned short* w1h = (unsigned short*)(ws + off); off += 16384;
    unsigned short* w1l = (unsigned short*)(ws + off); off += 16384;
    unsigned short* w2h = (unsigned short*)(ws + off); off += 131072;
    unsigned short* w2l = (unsigned short*)(ws + off); off += 131072;
    unsigned short* wth = (unsigned short*)(ws + off); off += 16384;
    unsigned short* wtl = (unsigned short*)(ws + off); off += 16384;
    unsigned short* xh  = (unsigned short*)(ws + off); off += (size_t)M_PAD * 32 / 2;
    unsigned short* xl  = (unsigned short*)(ws + off); off += (size_t)M_PAD * 32 / 2;
    unsigned short* h0h = (unsigned short*)(ws + off); off += (size_t)M_PAD * 32 / 2;
    unsigned short* h0l = (unsigned short*)(ws + off); off += (size_t)M_PAD * 32 / 2;
    unsigned short* h1h = (unsigned short*)(ws + off); off += (size_t)M_PAD * 256 / 2;
    unsigned short* h1l = (unsigned short*)(ws + off); off += (size_t)M_PAD * 256 / 2;

    const int EH = N_EDGES * 4;
    const dim3 gg(32, 98);   // 32 col-strips x ceil(1564/16) row-groups

    // ---- CSR build (by dst) ----
    hipMemsetAsync(deg, 0, 25600 * sizeof(int), stream);
    hipMemsetAsync(cursor, 0, 25600 * sizeof(int), stream);
    k_deg<<<(N_EDGES + 255) / 256, 256, 0, stream>>>(edge_idx, deg);
    k_scan<<<1, 256, 0, stream>>>(deg, rowptr);
    k_scatter<<<(N_EDGES + 255) / 256, 256, 0, stream>>>(edge_idx, rowptr, cursor, csrc, epos);

    // ---- weight prep ----
    k_wsplit<IN_DIM><<<(IN_DIM * 1024 + 255) / 256, 256, 0, stream>>>(gat1_w, w1h, w1l);
    k_wsplit<HIDD><<<(HIDD * 1024 + 255) / 256, 256, 0, stream>>>(gat2_w, w2h, w2l);
    k_w2perm<<<(32 * 1024 + 255) / 256, 256, 0, stream>>>(enc_w2, wth, wtl);
    k_xsplit<<<(N_NODES * 32 + 255) / 256, 256, 0, stream>>>(x, enc_b2, xh, xl, xb);

    // ---- NNConv ----
    hipMemsetAsync(agg, 0, (800000 + 25600) * sizeof(float), stream);
    k_gemm<IN_DIM><<<gg, 256, 0, stream>>>(xh, xl, wth, wtl, T16);
    k_msg<<<N_EDGES / 8, 256, 0, stream>>>(edge_attr, enc_w1, enc_b1, edge_idx, T16, xb, agg, cntf);
    k_h0<<<N_NODES / 8, 256, 0, stream>>>(x, root_w, nn_bias, agg, cntf, h0h, h0l);

    // ---- GAT layer 1 ----
    k_gemm<IN_DIM><<<gg, 256, 0, stream>>>(h0h, h0l, w1h, w1l, hfrag);
    k_esed<<<N_NODES, 256, 0, stream>>>(hfrag, gat1_asrc, gat1_adst, esb, edb);
    hipMemsetAsync(den, 0, 100000 * sizeof(float), stream);
    k_minit<<<(N_NODES * 4 + 255) / 256, 256, 0, stream>>>(esb, edb, mkey);
    k_mmax<<<(EH + 255) / 256, 256, 0, stream>>>(edge_idx, esb, edb, mkey);
    k_watt<<<(EH + 255) / 256, 256, 0, stream>>>(edge_idx, epos, esb, edb, mkey, wv, den);
    k_gat<false, true><<<N_NODES, 256, 0, stream>>>(rowptr, csrc, esb, edb, mkey, den, wv,
                                                    hfrag, gat1_b, nullptr, h1h, h1l);

    // ---- GAT layer 2 ----
    k_gemm<HIDD><<<gg, 256, 0, stream>>>(h1h, h1l, w2h, w2l, hfrag);
    k_esed<<<N_NODES, 256, 0, stream>>>(hfrag, gat2_asrc, gat2_adst, esb, edb);
    hipMemsetAsync(den, 0, 100000 * sizeof(float), stream);
    k_minit<<<(N_NODES * 4 + 255) / 256, 256, 0, stream>>>(esb, edb, mkey);
    k_mmax<<<(EH + 255) / 256, 256, 0, stream>>>(edge_idx, esb, edb, mkey);
    k_watt<<<(EH + 255) / 256, 256, 0, stream>>>(edge_idx, epos, esb, edb, mkey, wv, den);
    k_gat<true, false><<<N_NODES, 256, 0, stream>>>(rowptr, csrc, esb, edb, mkey, den, wv,
                                                    hfrag, gat2_b, h2, nullptr, nullptr);

    // ---- heads ----
    k_wire<<<KWIRE / 4, 256, 0, stream>>>(wire_mask, h2, wire_w, wire_b, out);
    hipMemsetAsync(pooled, 0, (NGRAPH * 256 + NGRAPH) * sizeof(float), stream);
    k_pool<<<(N_NODES + POOL_NB - 1) / POOL_NB, 256, 0, stream>>>(h2, batch, pooled, gcnt);
    k_act<<<NGRAPH * NACT / 4, 256, 0, stream>>>(pooled, gcnt, act_w, act_b, out);
}

// Round 10
// 551.667 us; speedup vs baseline: 1.2774x; 1.2326x over previous
//
#include <hip/hip_runtime.h>
#include <hip/hip_fp16.h>

#define N_NODES 25000
#define M_PAD   25024            // multiple of 16 (1564 tiles)
#define N_TILES 1564
#define N_EDGES 300000
#define IN_DIM  32
#define EDFD    16
#define HIDD    256
#define HEADS   4
#define NACT    16
#define NGRAPH  64
#define KWIRE   1024
#define POOL_NB 64

typedef _Float16 half8v __attribute__((ext_vector_type(8)));
typedef __attribute__((ext_vector_type(4))) float f32x4;

// ---------------------------------------------------------------- helpers
__device__ __forceinline__ float leaky(float v) { return v > 0.f ? v : 0.2f * v; }
__device__ __forceinline__ int fkey(float f) {
    int b = __float_as_int(f);
    b ^= (b >> 31) & 0x7fffffff;
    return b;
}
__device__ __forceinline__ float funkey(int b) {
    b ^= (b >> 31) & 0x7fffffff;
    return __int_as_float(b);
}

// ---------------------------------------------------------------- CSR build
__global__ __launch_bounds__(256) void k_deg(const int* __restrict__ ei, int* __restrict__ deg) {
    int e = blockIdx.x * 256 + threadIdx.x;
    if (e >= N_EDGES) return;
    atomicAdd(&deg[ei[N_EDGES + e]], 1);
}

__global__ __launch_bounds__(256) void k_scan(const int* __restrict__ deg, int* __restrict__ rowptr) {
    __shared__ int part[256];
    int t = threadIdx.x;
    const int CH = 98;
    int base = t * CH;
    int s = 0;
    for (int i = 0; i < CH; ++i) {
        int idx = base + i;
        if (idx < N_NODES) s += deg[idx];
    }
    part[t] = s;
    __syncthreads();
    if (t == 0) {
        int run = 0;
        for (int i = 0; i < 256; ++i) { int v = part[i]; part[i] = run; run += v; }
    }
    __syncthreads();
    int run = part[t];
    for (int i = 0; i < CH; ++i) {
        int idx = base + i;
        if (idx < N_NODES) { rowptr[idx] = run; run += deg[idx]; }
    }
    if (N_NODES >= base && N_NODES < base + CH) rowptr[N_NODES] = run;
}

__global__ __launch_bounds__(256) void k_scatter(const int* __restrict__ ei,
                                                 const int* __restrict__ rowptr,
                                                 int* __restrict__ cursor,
                                                 int* __restrict__ csrc,
                                                 int* __restrict__ epos) {
    int e = blockIdx.x * 256 + threadIdx.x;
    if (e >= N_EDGES) return;
    int dst = ei[N_EDGES + e];
    int pos = atomicAdd(&cursor[dst], 1);
    int r = rowptr[dst] + pos;
    csrc[r] = ei[e];
    epos[e] = r;
}

// ---------------------------------------------------------------- weight prep (fp16, transposed)
template <int K>
__global__ __launch_bounds__(256) void k_wcvt(const float* __restrict__ W,
                                              __half* __restrict__ Wt) {
    int i = blockIdx.x * 256 + threadIdx.x;
    if (i >= K * 1024) return;
    int k = i >> 10, n = i & 1023;
    Wt[(size_t)n * K + k] = __float2half(W[i]);
}

// enc_w2 [32][1024] (j, i*32+o) -> wtt [1024][32]: wtt[co= j*32+o][i]
__global__ __launch_bounds__(256) void k_w2perm(const float* __restrict__ w2,
                                                __half* __restrict__ Wt) {
    int idx = blockIdx.x * 256 + threadIdx.x;   // co*32 + i
    if (idx >= 32 * 1024) return;
    int co = idx >> 5, i = idx & 31;
    Wt[idx] = __float2half(w2[(co >> 5) * 1024 + i * 32 + (co & 31)]);
}

// folded attention vectors: wa1[h*32+i] = sum_d W1[i, h*256+d]*asrc[h,d]
__global__ __launch_bounds__(128) void k_wa1(const float* __restrict__ W1,
                                             const float* __restrict__ asrc,
                                             const float* __restrict__ adst,
                                             float* __restrict__ wa,
                                             float* __restrict__ wd) {
    int t = threadIdx.x;            // h*32+i
    int h = t >> 5, i = t & 31;
    float s = 0.f, sd = 0.f;
    for (int d = 0; d < 256; ++d) {
        float w = W1[i * 1024 + h * 256 + d];
        s  += w * asrc[h * 256 + d];
        sd += w * adst[h * 256 + d];
    }
    wa[t] = s; wd[t] = sd;
}

__global__ __launch_bounds__(256) void k_wa2(const float* __restrict__ W2,
                                             const float* __restrict__ asrc,
                                             const float* __restrict__ adst,
                                             float* __restrict__ wa,
                                             float* __restrict__ wd) {
    int idx = blockIdx.x * 256 + threadIdx.x;   // h*256+i
    if (idx >= 1024) return;
    int h = idx >> 8, i = idx & 255;
    float s = 0.f, sd = 0.f;
    for (int d = 0; d < 256; ++d) {
        float w = W2[i * 1024 + h * 256 + d];
        s  += w * asrc[h * 256 + d];
        sd += w * adst[h * 256 + d];
    }
    wa[idx] = s; wd[idx] = sd;
}

// x [N][32] -> xf fp16 + xb[n,o]
__global__ __launch_bounds__(256) void k_xcvt(const float* __restrict__ x,
                                              const float* __restrict__ b2,
                                              __half* __restrict__ xf,
                                              float* __restrict__ xb) {
    int idx = blockIdx.x * 256 + threadIdx.x;
    if (idx >= N_NODES * 32) return;
    int n = idx >> 5, o = idx & 31;
    xf[idx] = __float2half(x[idx]);
    float s = 0.f;
    for (int i = 0; i < 32; ++i) s += x[n * 32 + i] * b2[i * 32 + o];
    xb[idx] = s;
}

// ---------------------------------------------------------------- NNConv edge pass
__global__ __launch_bounds__(256) void k_msg(const float* __restrict__ ea,
                                             const float* __restrict__ w1,
                                             const float* __restrict__ b1,
                                             const int* __restrict__ ei,
                                             const __half* __restrict__ T,
                                             const float* __restrict__ xb,
                                             float* __restrict__ agg,
                                             float* __restrict__ cntf) {
    __shared__ float hb[8][IN_DIM];
    int t = threadIdx.x;
    int eg = t >> 5, o = t & 31;
    int e = blockIdx.x * 8 + eg;
    if (e < N_EDGES) {
        float a = b1[o];
        for (int k = 0; k < EDFD; ++k) a += ea[e * EDFD + k] * w1[k * 32 + o];
        hb[eg][o] = fmaxf(a, 0.f);
    }
    __syncthreads();
    if (e < N_EDGES) {
        int src = ei[e], dst = ei[N_EDGES + e];
        const __half* Tp = T + (size_t)src * 1024;
        float m = xb[src * IN_DIM + o];
        #pragma unroll
        for (int j = 0; j < IN_DIM; ++j) m += hb[eg][j] * __half2float(Tp[j * 32 + o]);
        atomicAdd(&agg[dst * IN_DIM + o], m);
        if (o == 0) atomicAdd(&cntf[dst], 1.f);
    }
}

// h0 = relu(agg/cnt + x@root_w + bias) -> fp16
__global__ __launch_bounds__(256) void k_h0(const float* __restrict__ x,
                                            const float* __restrict__ root_w,
                                            const float* __restrict__ nn_bias,
                                            const float* __restrict__ agg,
                                            const float* __restrict__ cntf,
                                            __half* __restrict__ h0f) {
    int t = threadIdx.x;
    int ng = t >> 5, o = t & 31;
    int n = blockIdx.x * 8 + ng;
    if (n >= N_NODES) return;
    float s = nn_bias[o];
    for (int k = 0; k < IN_DIM; ++k) s += x[n * IN_DIM + k] * root_w[k * 32 + o];
    float c = fmaxf(cntf[n], 1.f);
    s += agg[n * IN_DIM + o] / c;
    h0f[n * IN_DIM + o] = __float2half(fmaxf(s, 0.f));
}

// ---------------------------------------------------------------- fp16 MFMA GEMM
// C[M_PAD,1024](fp16) = A @ Wt^T. K = contraction, RS = A row stride, HK = per-head A col offset
// (output col co -> head = co>>8, A cols [head*HK, head*HK+K)). XCD-bijective block remap.
template <int K, int RS, int HK>
__global__ __launch_bounds__(256) void k_gemm(const __half* __restrict__ A,
                                              const __half* __restrict__ Wt,
                                              __half* __restrict__ C) {
    constexpr int KS = K / 32;
    constexpr int CB = K * 2;                 // bytes per B column
    __shared__ __half bs[32 * K];
    __shared__ __half cst[4][16 * 36];        // padded stride vs 32 -> bank spread
    int t = threadIdx.x, wid = t >> 6, lane = t & 63;
    int lr = lane & 15, lk = (lane >> 4) * 8;

    // bijective XCD remap: all 32 col-strips of a row-group land on one XCD
    int bid = blockIdx.x;
    int xcd = bid & 7, j = bid >> 3;
    int sx = j & 31;
    int y = ((j >> 5) << 3) | xcd;            // 0..103
    int n0 = sx * 32;
    int head = (HK > 0) ? (n0 >> 8) : 0;

    // stage B strip (32 cols x K fp16), XOR swizzle byte ^= ((col&7)<<4)
    {
        const char* src = (const char*)(Wt + (size_t)n0 * K);
        for (int i = t * 16; i < 32 * K * 2; i += 256 * 16) {
            int sb = i ^ (((i / CB) & 7) << 4);
            *(float4*)((char*)bs + sb) = *(const float4*)(src + i);
        }
    }
    __syncthreads();

    const int swz = (lr & 7) << 4;

    int tb = (y * 4 + wid) * 4;               // 4 row-tiles per wave
    for (int pp = 0; pp < 4; pp += 2) {
        int tA = tb + pp;
        if (tA >= N_TILES) break;
        int mA = tA * 16, mB = mA + 16;       // N_TILES even -> pair valid
        const __half* pA = A + (size_t)(mA + lr) * RS + head * HK + lk;
        const __half* pB = A + (size_t)(mB + lr) * RS + head * HK + lk;

        f32x4 acc[2][2];
        #pragma unroll
        for (int i = 0; i < 2; ++i)
            #pragma unroll
            for (int c = 0; c < 2; ++c)
                acc[i][c] = (f32x4){0.f, 0.f, 0.f, 0.f};

        #pragma unroll
        for (int ks = 0; ks < KS; ++ks) {
            half8v aA = *(const half8v*)(pA + ks * 32);
            half8v aB = *(const half8v*)(pB + ks * 32);
            half8v b0 = *(const half8v*)((const char*)bs + ((( 0 + lr) * CB + lk * 2 + ks * 64) ^ swz));
            half8v b1 = *(const half8v*)((const char*)bs + (((16 + lr) * CB + lk * 2 + ks * 64) ^ swz));
            acc[0][0] = __builtin_amdgcn_mfma_f32_16x16x32_f16(aA, b0, acc[0][0], 0, 0, 0);
            acc[0][1] = __builtin_amdgcn_mfma_f32_16x16x32_f16(aA, b1, acc[0][1], 0, 0, 0);
            acc[1][0] = __builtin_amdgcn_mfma_f32_16x16x32_f16(aB, b0, acc[1][0], 0, 0, 0);
            acc[1][1] = __builtin_amdgcn_mfma_f32_16x16x32_f16(aB, b1, acc[1][1], 0, 0, 0);
        }

        int rbase = (lane >> 4) * 4;
        #pragma unroll
        for (int ti = 0; ti < 2; ++ti) {
            #pragma unroll
            for (int c = 0; c < 2; ++c)
                #pragma unroll
                for (int r = 0; r < 4; ++r)
                    cst[wid][(rbase + r) * 36 + c * 16 + lr] = __float2half(acc[ti][c][r]);
            int m0 = ti ? mB : mA;
            // wave-private staging; compiler orders via lgkmcnt
            #pragma unroll
            for (int p = 0; p < 2; ++p) {
                int row = p * 8 + (lane >> 3), hb = lane & 7;
                float2 v = *(const float2*)((const char*)&cst[wid][0] + row * 72 + hb * 8);
                *(float2*)((char*)C + ((size_t)(m0 + row) * 1024 + n0) * 2 + hb * 8) = v;
            }
        }
    }
}

// ---------------------------------------------------------------- attention scalars
// layer1: es/ed from h0 via folded wa1/wd1 (32-dim dots)
__global__ __launch_bounds__(256) void k_esed1(const __half* __restrict__ h0f,
                                               const float* __restrict__ wa,
                                               const float* __restrict__ wd,
                                               float* __restrict__ es,
                                               float* __restrict__ ed) {
    int idx = blockIdx.x * 256 + threadIdx.x;   // n*4+h
    if (idx >= N_NODES * 4) return;
    int n = idx >> 2, h = idx & 3;
    float s = 0.f, d2 = 0.f;
    #pragma unroll
    for (int i = 0; i < 32; ++i) {
        float v = __half2float(h0f[n * 32 + i]);
        s  += v * wa[h * 32 + i];
        d2 += v * wd[h * 32 + i];
    }
    es[idx] = s; ed[idx] = d2;
}

// layer2: es/ed from h1 via wa2/wd2 (256-dim dots), block per node
__global__ __launch_bounds__(256) void k_esed2(const __half* __restrict__ h1f,
                                               const float* __restrict__ wa,
                                               const float* __restrict__ wd,
                                               float* __restrict__ es,
                                               float* __restrict__ ed) {
    int n = blockIdx.x;
    int h = threadIdx.x >> 6, lane = threadIdx.x & 63;
    float s = 0.f, d2 = 0.f;
    for (int d = lane; d < 256; d += 64) {
        float v = __half2float(h1f[(size_t)n * 256 + d]);
        s  += v * wa[h * 256 + d];
        d2 += v * wd[h * 256 + d];
    }
    #pragma unroll
    for (int off = 32; off; off >>= 1) {
        s  += __shfl_down(s, off);
        d2 += __shfl_down(d2, off);
    }
    if (lane == 0) { es[n * 4 + h] = s; ed[n * 4 + h] = d2; }
}

__global__ __launch_bounds__(256) void k_minit(const float* __restrict__ es,
                                               const float* __restrict__ ed,
                                               int* __restrict__ mkey) {
    int i = blockIdx.x * 256 + threadIdx.x;
    if (i >= N_NODES * 4) return;
    mkey[i] = fkey(leaky(es[i] + ed[i]));
}

__global__ __launch_bounds__(256) void k_mmax(const int* __restrict__ ei,
                                              const float* __restrict__ es,
                                              const float* __restrict__ ed,
                                              int* __restrict__ mkey) {
    int idx = blockIdx.x * 256 + threadIdx.x;
    if (idx >= N_EDGES * 4) return;
    int e = idx >> 2, h = idx & 3;
    int src = ei[e], dst = ei[N_EDGES + e];
    atomicMax(&mkey[dst * 4 + h], fkey(leaky(es[src * 4 + h] + ed[dst * 4 + h])));
}

__global__ __launch_bounds__(256) void k_watt(const int* __restrict__ ei,
                                              const int* __restrict__ epos,
                                              const float* __restrict__ es,
                                              const float* __restrict__ ed,
                                              const int* __restrict__ mkey,
                                              float* __restrict__ wv,
                                              float* __restrict__ den) {
    int idx = blockIdx.x * 256 + threadIdx.x;
    if (idx >= N_EDGES * 4) return;
    int e = idx >> 2, h = idx & 3;
    int src = ei[e], dst = ei[N_EDGES + e];
    float v = leaky(es[src * 4 + h] + ed[dst * 4 + h]);
    float w = __expf(v - funkey(mkey[dst * 4 + h]));
    wv[(size_t)epos[e] * 4 + h] = w;
    atomicAdd(&den[dst * 4 + h], w);
}

// ---------------------------------------------------------------- pre-GEMM aggregation
// layer1: agg0[dst, h*32+i] = ( w_self*h0[dst] + sum_e w_e*h0[src] )/den   (32-dim)
__global__ __launch_bounds__(256) void k_agg1(const int* __restrict__ rowptr,
                                              const int* __restrict__ csrc,
                                              const float* __restrict__ es,
                                              const float* __restrict__ ed,
                                              const int* __restrict__ mkey,
                                              const float* __restrict__ denb,
                                              const float* __restrict__ wv,
                                              const __half* __restrict__ h0f,
                                              __half* __restrict__ agg0) {
    int dst = blockIdx.x * 4 + (threadIdx.x >> 6);
    if (dst >= N_NODES) return;
    int lane = threadIdx.x & 63;
    int h = lane >> 4, i2 = lane & 15;
    float m = funkey(mkey[dst * 4 + h]);
    float vself = leaky(es[dst * 4 + h] + ed[dst * 4 + h]);
    float ws = __expf(vself - m);
    float dn = denb[dst * 4 + h] + ws;
    int r0 = rowptr[dst], r1 = rowptr[dst + 1];

    __half2 hv = *(const __half2*)(h0f + (size_t)dst * 32 + i2 * 2);
    float2 f = __half22float2(hv);
    float ax = ws * f.x, ay = ws * f.y;
    for (int r = r0; r < r1; ++r) {
        int src = csrc[r];
        float w = wv[(size_t)r * 4 + h];
        __half2 sv = *(const __half2*)(h0f + (size_t)src * 32 + i2 * 2);
        float2 g = __half22float2(sv);
        ax += w * g.x; ay += w * g.y;
    }
    float inv = 1.f / (dn + 1e-16f);
    *(__half2*)(agg0 + (size_t)dst * 128 + h * 32 + i2 * 2) =
        __float22half2_rn(make_float2(ax * inv, ay * inv));
}

// layer2: agg1[dst, h*256+d] -- reads each 512B h1 row once, 4 head-accumulators
__global__ __launch_bounds__(256) void k_agg2(const int* __restrict__ rowptr,
                                              const int* __restrict__ csrc,
                                              const float* __restrict__ es,
                                              const float* __restrict__ ed,
                                              const int* __restrict__ mkey,
                                              const float* __restrict__ denb,
                                              const float* __restrict__ wv,
                                              const __half* __restrict__ h1f,
                                              __half* __restrict__ agg1) {
    int dst = blockIdx.x * 4 + (threadIdx.x >> 6);
    if (dst >= N_NODES) return;
    int lane = threadIdx.x & 63;
    float ws[4], dn[4];
    #pragma unroll
    for (int h = 0; h < 4; ++h) {
        float m = funkey(mkey[dst * 4 + h]);
        float vself = leaky(es[dst * 4 + h] + ed[dst * 4 + h]);
        ws[h] = __expf(vself - m);
        dn[h] = denb[dst * 4 + h] + ws[h];
    }
    int r0 = rowptr[dst], r1 = rowptr[dst + 1];

    float acc[4][4];
    {
        float2 q = *(const float2*)(h1f + (size_t)dst * 256 + lane * 4);
        const __half2* hq = (const __half2*)&q;
        float2 f0 = __half22float2(hq[0]), f1 = __half22float2(hq[1]);
        #pragma unroll
        for (int h = 0; h < 4; ++h) {
            acc[h][0] = ws[h] * f0.x; acc[h][1] = ws[h] * f0.y;
            acc[h][2] = ws[h] * f1.x; acc[h][3] = ws[h] * f1.y;
        }
    }
    for (int r = r0; r < r1; ++r) {
        int src = csrc[r];
        float4 w4 = *(const float4*)(wv + (size_t)r * 4);
        float2 q = *(const float2*)(h1f + (size_t)src * 256 + lane * 4);
        const __half2* hq = (const __half2*)&q;
        float2 f0 = __half22float2(hq[0]), f1 = __half22float2(hq[1]);
        acc[0][0] += w4.x * f0.x; acc[0][1] += w4.x * f0.y; acc[0][2] += w4.x * f1.x; acc[0][3] += w4.x * f1.y;
        acc[1][0] += w4.y * f0.x; acc[1][1] += w4.y * f0.y; acc[1][2] += w4.y * f1.x; acc[1][3] += w4.y * f1.y;
        acc[2][0] += w4.z * f0.x; acc[2][1] += w4.z * f0.y; acc[2][2] += w4.z * f1.x; acc[2][3] += w4.z * f1.y;
        acc[3][0] += w4.w * f0.x; acc[3][1] += w4.w * f0.y; acc[3][2] += w4.w * f1.x; acc[3][3] += w4.w * f1.y;
    }
    #pragma unroll
    for (int h = 0; h < 4; ++h) {
        float inv = 1.f / (dn[h] + 1e-16f);
        __half2 o0 = __float22half2_rn(make_float2(acc[h][0] * inv, acc[h][1] * inv));
        __half2 o1 = __float22half2_rn(make_float2(acc[h][2] * inv, acc[h][3] * inv));
        __half2* op = (__half2*)(agg1 + (size_t)dst * 1024 + h * 256 + lane * 4);
        op[0] = o0; op[1] = o1;
    }
}

// ---------------------------------------------------------------- head-mean finales
__global__ __launch_bounds__(256) void k_fin1(const __half* __restrict__ pre,
                                              const float* __restrict__ b,
                                              __half* __restrict__ h1f) {
    int idx = blockIdx.x * 256 + threadIdx.x;   // n*256+d
    if (idx >= N_NODES * 256) return;
    int n = idx >> 8, d = idx & 255;
    const __half* p = pre + (size_t)n * 1024 + d;
    float s = __half2float(p[0]) + __half2float(p[256]) + __half2float(p[512]) + __half2float(p[768]);
    h1f[idx] = __float2half(fmaxf(0.25f * s + b[d], 0.f));
}

__global__ __launch_bounds__(256) void k_fin2(const __half* __restrict__ pre,
                                              const float* __restrict__ b,
                                              float* __restrict__ h2) {
    int idx = blockIdx.x * 256 + threadIdx.x;
    if (idx >= N_NODES * 256) return;
    int n = idx >> 8, d = idx & 255;
    const __half* p = pre + (size_t)n * 1024 + d;
    float s = __half2float(p[0]) + __half2float(p[256]) + __half2float(p[512]) + __half2float(p[768]);
    h2[idx] = fmaxf(0.25f * s + b[d], 0.f);
}

// ---------------------------------------------------------------- heads
__global__ __launch_bounds__(256) void k_wire(const int* __restrict__ wm,
                                              const float* __restrict__ h2,
                                              const float* __restrict__ ww,
                                              const float* __restrict__ wb,
                                              float* __restrict__ out) {
    int k = blockIdx.x * 4 + (threadIdx.x >> 6);
    int lane = threadIdx.x & 63;
    if (k >= KWIRE) return;
    int n = wm[k];
    float s = 0.f;
    for (int d = lane; d < 256; d += 64) s += h2[(size_t)n * 256 + d] * ww[d];
    #pragma unroll
    for (int off = 32; off; off >>= 1) s += __shfl_down(s, off);
    if (lane == 0) out[k] = s + wb[0];
}

__global__ __launch_bounds__(256) void k_pool(const float* __restrict__ h2,
                                              const int* __restrict__ batch,
                                              float* __restrict__ pooled,
                                              float* __restrict__ gcnt) {
    int n0 = blockIdx.x * POOL_NB;
    int n1 = n0 + POOL_NB; if (n1 > N_NODES) n1 = N_NODES;
    int d = threadIdx.x;
    int cur = batch[n0];
    float acc = 0.f, cnt = 0.f;
    for (int n = n0; n < n1; ++n) {
        int g = batch[n];
        if (g != cur) {
            atomicAdd(&pooled[cur * 256 + d], acc);
            if (d == 0) atomicAdd(&gcnt[cur], cnt);
            acc = 0.f; cnt = 0.f; cur = g;
        }
        acc += h2[(size_t)n * 256 + d];
        cnt += 1.f;
    }
    atomicAdd(&pooled[cur * 256 + d], acc);
    if (d == 0) atomicAdd(&gcnt[cur], cnt);
}

__global__ __launch_bounds__(256) void k_act(const float* __restrict__ pooled,
                                             const float* __restrict__ gcnt,
                                             const float* __restrict__ aw,
                                             const float* __restrict__ ab,
                                             float* __restrict__ out) {
    int u = blockIdx.x * 4 + (threadIdx.x >> 6);
    int lane = threadIdx.x & 63;
    if (u >= NGRAPH * NACT) return;
    int g = u >> 4, a = u & 15;
    float c = fmaxf(gcnt[g], 1.f);
    float s = 0.f;
    for (int d = lane; d < 256; d += 64) s += pooled[g * 256 + d] * aw[d * 16 + a];
    #pragma unroll
    for (int off = 32; off; off >>= 1) s += __shfl_down(s, off);
    if (lane == 0) out[KWIRE + u] = s / c + ab[a];
}

// ---------------------------------------------------------------- launch
extern "C" void kernel_launch(void* const* d_in, const int* in_sizes, int n_in,
                              void* d_out, int out_size, void* d_ws, size_t ws_size,
                              hipStream_t stream) {
    const float* x        = (const float*)d_in[0];
    const float* edge_attr= (const float*)d_in[1];
    const int*   wire_mask= (const int*)d_in[2];
    const int*   edge_idx = (const int*)d_in[3];
    const int*   batch    = (const int*)d_in[4];
    const float* enc_w1   = (const float*)d_in[5];
    const float* enc_b1   = (const float*)d_in[6];
    const float* enc_w2   = (const float*)d_in[7];
    const float* enc_b2   = (const float*)d_in[8];
    const float* root_w   = (const float*)d_in[9];
    const float* nn_bias  = (const float*)d_in[10];
    const float* gat1_w   = (const float*)d_in[11];
    const float* gat1_asrc= (const float*)d_in[12];
    const float* gat1_adst= (const float*)d_in[13];
    const float* gat1_b   = (const float*)d_in[14];
    const float* gat2_w   = (const float*)d_in[15];
    const float* gat2_asrc= (const float*)d_in[16];
    const float* gat2_adst= (const float*)d_in[17];
    const float* gat2_b   = (const float*)d_in[18];
    const float* wire_w   = (const float*)d_in[19];
    const float* wire_b   = (const float*)d_in[20];
    const float* act_w    = (const float*)d_in[21];
    const float* act_b    = (const float*)d_in[22];
    float* out = (float*)d_out;

    float* ws = (float*)d_ws;
    size_t off = 0;
    __half* big   = (__half*)(ws + off); off += (size_t)M_PAD * 1024 / 2;  // T16 -> pre1 -> pre2
    __half* agg1f = (__half*)(ws + off); off += (size_t)M_PAD * 1024 / 2;
    __half* agg0f = (__half*)(ws + off); off += (size_t)M_PAD * 128 / 2;
    __half* h0f   = (__half*)(ws + off); off += (size_t)M_PAD * 32 / 2;
    __half* h1f   = (__half*)(ws + off); off += (size_t)M_PAD * 256 / 2;
    __half* xf    = (__half*)(ws + off); off += (size_t)M_PAD * 32 / 2;
    float* xb     = ws + off; off += 800000;
    float* agg    = ws + off; off += 800000;
    float* cntf   = ws + off; off += 25600;
    float* esb    = ws + off; off += 100000;
    float* edb    = ws + off; off += 100000;
    float* h2     = ws + off; off += 6400000;
    float* pooled = ws + off; off += NGRAPH * 256;
    float* gcnt   = ws + off; off += NGRAPH;
    int* deg      = (int*)(ws + off); off += 25600;
    int* rowptr   = (int*)(ws + off); off += 25600;
    int* cursor   = (int*)(ws + off); off += 25600;
    int* csrc     = (int*)(ws + off); off += N_EDGES;
    int* epos     = (int*)(ws + off); off += N_EDGES;
    int* mkey     = (int*)(ws + off); off += 100000;
    float* den    = ws + off; off += 100000;
    float* wv     = ws + off; off += (size_t)N_EDGES * 4;
    __half* wt1   = (__half*)(ws + off); off += 16384;   // [1024][32]
    __half* wt2   = (__half*)(ws + off); off += 131072;  // [1024][256]
    __half* wtt   = (__half*)(ws + off); off += 16384;   // enc_w2 perm [1024][32]
    float* wa1    = ws + off; off += 128;
    float* wd1    = ws + off; off += 128;
    float* wa2    = ws + off; off += 1024;
    float* wd2    = ws + off; off += 1024;

    const int EH = N_EDGES * 4;
    const int GB = 3328;   // 8 xcd x 13 ygroups x 32 strips (bijective remap in-kernel)

    // ---- CSR build ----
    hipMemsetAsync(deg, 0, 25600 * sizeof(int), stream);
    hipMemsetAsync(cursor, 0, 25600 * sizeof(int), stream);
    k_deg<<<(N_EDGES + 255) / 256, 256, 0, stream>>>(edge_idx, deg);
    k_scan<<<1, 256, 0, stream>>>(deg, rowptr);
    k_scatter<<<(N_EDGES + 255) / 256, 256, 0, stream>>>(edge_idx, rowptr, cursor, csrc, epos);

    // ---- weight prep ----
    k_wcvt<IN_DIM><<<(IN_DIM * 1024 + 255) / 256, 256, 0, stream>>>(gat1_w, wt1);
    k_wcvt<HIDD><<<(HIDD * 1024 + 255) / 256, 256, 0, stream>>>(gat2_w, wt2);
    k_w2perm<<<(32 * 1024 + 255) / 256, 256, 0, stream>>>(enc_w2, wtt);
    k_xcvt<<<(N_NODES * 32 + 255) / 256, 256, 0, stream>>>(x, enc_b2, xf, xb);
    k_wa1<<<1, 128, 0, stream>>>(gat1_w, gat1_asrc, gat1_adst, wa1, wd1);
    k_wa2<<<4, 256, 0, stream>>>(gat2_w, gat2_asrc, gat2_adst, wa2, wd2);

    // ---- NNConv ----
    hipMemsetAsync(agg, 0, (800000 + 25600) * sizeof(float), stream);
    k_gemm<IN_DIM, 32, 0><<<GB, 256, 0, stream>>>(xf, wtt, big);      // T16
    k_msg<<<N_EDGES / 8, 256, 0, stream>>>(edge_attr, enc_w1, enc_b1, edge_idx, big, xb, agg, cntf);
    k_h0<<<N_NODES / 8, 256, 0, stream>>>(x, root_w, nn_bias, agg, cntf, h0f);

    // ---- GAT layer 1 (pre-aggregation form) ----
    k_esed1<<<(N_NODES * 4 + 255) / 256, 256, 0, stream>>>(h0f, wa1, wd1, esb, edb);
    k_minit<<<(N_NODES * 4 + 255) / 256, 256, 0, stream>>>(esb, edb, mkey);
    k_mmax<<<(EH + 255) / 256, 256, 0, stream>>>(edge_idx, esb, edb, mkey);
    hipMemsetAsync(den, 0, 100000 * sizeof(float), stream);
    k_watt<<<(EH + 255) / 256, 256, 0, stream>>>(edge_idx, epos, esb, edb, mkey, wv, den);
    k_agg1<<<(N_NODES + 3) / 4, 256, 0, stream>>>(rowptr, csrc, esb, edb, mkey, den, wv, h0f, agg0f);
    k_gemm<IN_DIM, 128, 32><<<GB, 256, 0, stream>>>(agg0f, wt1, big);  // pre1
    k_fin1<<<(N_NODES * 256 + 255) / 256, 256, 0, stream>>>(big, gat1_b, h1f);

    // ---- GAT layer 2 ----
    k_esed2<<<N_NODES, 256, 0, stream>>>(h1f, wa2, wd2, esb, edb);
    k_minit<<<(N_NODES * 4 + 255) / 256, 256, 0, stream>>>(esb, edb, mkey);
    k_mmax<<<(EH + 255) / 256, 256, 0, stream>>>(edge_idx, esb, edb, mkey);
    hipMemsetAsync(den, 0, 100000 * sizeof(float), stream);
    k_watt<<<(EH + 255) / 256, 256, 0, stream>>>(edge_idx, epos, esb, edb, mkey, wv, den);
    k_agg2<<<(N_NODES + 3) / 4, 256, 0, stream>>>(rowptr, csrc, esb, edb, mkey, den, wv, h1f, agg1f);
    k_gemm<HIDD, 1024, 256><<<GB, 256, 0, stream>>>(agg1f, wt2, big);  // pre2
    k_fin2<<<(N_NODES * 256 + 255) / 256, 256, 0, stream>>>(big, gat2_b, h2);

    // ---- heads ----
    k_wire<<<KWIRE / 4, 256, 0, stream>>>(wire_mask, h2, wire_w, wire_b, out);
    hipMemsetAsync(pooled, 0, (NGRAPH * 256 + NGRAPH) * sizeof(float), stream);
    k_pool<<<(N_NODES + POOL_NB - 1) / POOL_NB, 256, 0, stream>>>(h2, batch, pooled, gcnt);
    k_act<<<NGRAPH * NACT / 4, 256, 0, stream>>>(pooled, gcnt, act_w, act_b, out);
}

// Round 11
// 546.168 us; speedup vs baseline: 1.2902x; 1.0101x over previous
//
#include <hip/hip_runtime.h>
#include <hip/hip_fp16.h>

#define N_NODES 25000
#define M_PAD   25024            // multiple of 16 (1564 tiles)
#define N_TILES 1564
#define N_EDGES 300000
#define IN_DIM  32
#define EDFD    16
#define HIDD    256
#define HEADS   4
#define NACT    16
#define NGRAPH  64
#define KWIRE   1024
#define POOL_NB 64

typedef _Float16 half8v __attribute__((ext_vector_type(8)));
typedef __attribute__((ext_vector_type(4))) float f32x4;

// ---------------------------------------------------------------- helpers
__device__ __forceinline__ float leaky(float v) { return v > 0.f ? v : 0.2f * v; }
__device__ __forceinline__ int fkey(float f) {
    int b = __float_as_int(f);
    b ^= (b >> 31) & 0x7fffffff;
    return b;
}
__device__ __forceinline__ float funkey(int b) {
    b ^= (b >> 31) & 0x7fffffff;
    return __int_as_float(b);
}

// ---------------------------------------------------------------- CSR build (both directions, one pass)
__global__ __launch_bounds__(256) void k_deg2(const int* __restrict__ ei,
                                              int* __restrict__ deg,
                                              int* __restrict__ deg2) {
    int e = blockIdx.x * 256 + threadIdx.x;
    if (e >= N_EDGES) return;
    atomicAdd(&deg[ei[N_EDGES + e]], 1);   // by dst
    atomicAdd(&deg2[ei[e]], 1);            // by src
}

__global__ __launch_bounds__(256) void k_scan2(const int* __restrict__ degA, int* __restrict__ rpA,
                                               const int* __restrict__ degB, int* __restrict__ rpB) {
    const int* deg = blockIdx.x ? degB : degA;
    int* rowptr    = blockIdx.x ? rpB : rpA;
    __shared__ int part[256];
    int t = threadIdx.x;
    const int CH = 98;
    int base = t * CH;
    int s = 0;
    for (int i = 0; i < CH; ++i) {
        int idx = base + i;
        if (idx < N_NODES) s += deg[idx];
    }
    part[t] = s;
    __syncthreads();
    if (t == 0) {
        int run = 0;
        for (int i = 0; i < 256; ++i) { int v = part[i]; part[i] = run; run += v; }
    }
    __syncthreads();
    int run = part[t];
    for (int i = 0; i < CH; ++i) {
        int idx = base + i;
        if (idx < N_NODES) { rowptr[idx] = run; run += deg[idx]; }
    }
    if (N_NODES >= base && N_NODES < base + CH) rowptr[N_NODES] = run;
}

__global__ __launch_bounds__(256) void k_scatter2(const int* __restrict__ ei,
                                                  const int* __restrict__ rowptr,
                                                  const int* __restrict__ rowptr2,
                                                  int* __restrict__ cursor,
                                                  int* __restrict__ cursor2,
                                                  int* __restrict__ csrc,
                                                  int* __restrict__ epos,
                                                  int* __restrict__ cdst,
                                                  int* __restrict__ epos2) {
    int e = blockIdx.x * 256 + threadIdx.x;
    if (e >= N_EDGES) return;
    int src = ei[e], dst = ei[N_EDGES + e];
    int p1 = atomicAdd(&cursor[dst], 1);
    int r1 = rowptr[dst] + p1;
    csrc[r1] = src;
    epos[e] = r1;
    int p2 = atomicAdd(&cursor2[src], 1);
    int r2 = rowptr2[src] + p2;
    cdst[r2] = dst;
    epos2[e] = r2;
}

// ---------------------------------------------------------------- weight prep (fp16, transposed)
template <int K>
__global__ __launch_bounds__(256) void k_wcvt(const float* __restrict__ W,
                                              __half* __restrict__ Wt) {
    int i = blockIdx.x * 256 + threadIdx.x;
    if (i >= K * 1024) return;
    int k = i >> 10, n = i & 1023;
    Wt[(size_t)n * K + k] = __float2half(W[i]);
}

__global__ __launch_bounds__(256) void k_w2perm(const float* __restrict__ w2,
                                                __half* __restrict__ Wt) {
    int idx = blockIdx.x * 256 + threadIdx.x;   // co*32 + i
    if (idx >= 32 * 1024) return;
    int co = idx >> 5, i = idx & 31;
    Wt[idx] = __float2half(w2[(co >> 5) * 1024 + i * 32 + (co & 31)]);
}

__global__ __launch_bounds__(128) void k_wa1(const float* __restrict__ W1,
                                             const float* __restrict__ asrc,
                                             const float* __restrict__ adst,
                                             float* __restrict__ wa,
                                             float* __restrict__ wd) {
    int t = threadIdx.x;            // h*32+i
    int h = t >> 5, i = t & 31;
    float s = 0.f, sd = 0.f;
    for (int d = 0; d < 256; ++d) {
        float w = W1[i * 1024 + h * 256 + d];
        s  += w * asrc[h * 256 + d];
        sd += w * adst[h * 256 + d];
    }
    wa[t] = s; wd[t] = sd;
}

__global__ __launch_bounds__(256) void k_wa2(const float* __restrict__ W2,
                                             const float* __restrict__ asrc,
                                             const float* __restrict__ adst,
                                             float* __restrict__ wa,
                                             float* __restrict__ wd) {
    int idx = blockIdx.x * 256 + threadIdx.x;   // h*256+i
    if (idx >= 1024) return;
    int h = idx >> 8, i = idx & 255;
    float s = 0.f, sd = 0.f;
    for (int d = 0; d < 256; ++d) {
        float w = W2[i * 1024 + h * 256 + d];
        s  += w * asrc[h * 256 + d];
        sd += w * adst[h * 256 + d];
    }
    wa[idx] = s; wd[idx] = sd;
}

__global__ __launch_bounds__(256) void k_xcvt(const float* __restrict__ x,
                                              const float* __restrict__ b2,
                                              __half* __restrict__ xf,
                                              float* __restrict__ xb) {
    int idx = blockIdx.x * 256 + threadIdx.x;
    if (idx >= N_NODES * 32) return;
    int n = idx >> 5, o = idx & 31;
    xf[idx] = __float2half(x[idx]);
    float s = 0.f;
    for (int i = 0; i < 32; ++i) s += x[n * 32 + i] * b2[i * 32 + o];
    xb[idx] = s;
}

// ---------------------------------------------------------------- NNConv
// edge MLP: hEs[epos2[e]*32+o] = relu(ea@w1+b1)[o]  (stored in src-CSR order)
__global__ __launch_bounds__(256) void k_hedge(const float* __restrict__ ea,
                                               const float* __restrict__ w1,
                                               const float* __restrict__ b1,
                                               const int* __restrict__ epos2,
                                               __half* __restrict__ hEs) {
    int t = threadIdx.x;
    int eg = t >> 5, o = t & 31;
    int e = blockIdx.x * 8 + eg;
    if (e >= N_EDGES) return;
    float a = b1[o];
    for (int k = 0; k < EDFD; ++k) a += ea[e * EDFD + k] * w1[k * 32 + o];
    hEs[(size_t)epos2[e] * 32 + o] = __float2half(fmaxf(a, 0.f));
}

// src-ordered message pass: T[src] column loaded once per src; per out-edge 32 FMA + atomic
__global__ __launch_bounds__(256) void k_msg2(const int* __restrict__ rowptr2,
                                              const int* __restrict__ cdst,
                                              const __half* __restrict__ hEs,
                                              const __half* __restrict__ T,
                                              const float* __restrict__ xb,
                                              float* __restrict__ agg) {
    int g = threadIdx.x >> 5, o = threadIdx.x & 31;
    int src = blockIdx.x * 8 + g;
    if (src >= N_NODES) return;
    int r0 = rowptr2[src], r1 = rowptr2[src + 1];
    if (r0 == r1) return;
    float tcol[32];
    const __half* Tp = T + (size_t)src * 1024 + o;
    #pragma unroll
    for (int j = 0; j < 32; ++j) tcol[j] = __half2float(Tp[j * 32]);
    float xbv = xb[src * 32 + o];
    for (int r = r0; r < r1; ++r) {
        int dst = cdst[r];
        const __half2* hp2 = (const __half2*)(hEs + (size_t)r * 32);
        float m = xbv;
        #pragma unroll
        for (int jj = 0; jj < 16; ++jj) {
            float2 hv = __half22float2(hp2[jj]);
            m += hv.x * tcol[2 * jj] + hv.y * tcol[2 * jj + 1];
        }
        atomicAdd(&agg[dst * 32 + o], m);
    }
}

// h0 = relu(agg/deg + x@root_w + bias) -> fp16 ; deg from dst-CSR rowptr
__global__ __launch_bounds__(256) void k_h0(const float* __restrict__ x,
                                            const float* __restrict__ root_w,
                                            const float* __restrict__ nn_bias,
                                            const float* __restrict__ agg,
                                            const int* __restrict__ rowptr,
                                            __half* __restrict__ h0f) {
    int t = threadIdx.x;
    int ng = t >> 5, o = t & 31;
    int n = blockIdx.x * 8 + ng;
    if (n >= N_NODES) return;
    float s = nn_bias[o];
    for (int k = 0; k < IN_DIM; ++k) s += x[n * IN_DIM + k] * root_w[k * 32 + o];
    float c = fmaxf((float)(rowptr[n + 1] - rowptr[n]), 1.f);
    s += agg[n * IN_DIM + o] / c;
    h0f[n * IN_DIM + o] = __float2half(fmaxf(s, 0.f));
}

// ---------------------------------------------------------------- fp16 MFMA GEMM (unchanged from R10)
template <int K, int RS, int HK>
__global__ __launch_bounds__(256) void k_gemm(const __half* __restrict__ A,
                                              const __half* __restrict__ Wt,
                                              __half* __restrict__ C) {
    constexpr int KS = K / 32;
    constexpr int CB = K * 2;
    __shared__ __half bs[32 * K];
    __shared__ __half cst[4][16 * 36];
    int t = threadIdx.x, wid = t >> 6, lane = t & 63;
    int lr = lane & 15, lk = (lane >> 4) * 8;

    int bid = blockIdx.x;
    int xcd = bid & 7, j = bid >> 3;
    int sx = j & 31;
    int y = ((j >> 5) << 3) | xcd;
    int n0 = sx * 32;
    int head = (HK > 0) ? (n0 >> 8) : 0;

    {
        const char* src = (const char*)(Wt + (size_t)n0 * K);
        for (int i = t * 16; i < 32 * K * 2; i += 256 * 16) {
            int sb = i ^ (((i / CB) & 7) << 4);
            *(float4*)((char*)bs + sb) = *(const float4*)(src + i);
        }
    }
    __syncthreads();

    const int swz = (lr & 7) << 4;

    int tb = (y * 4 + wid) * 4;
    for (int pp = 0; pp < 4; pp += 2) {
        int tA = tb + pp;
        if (tA >= N_TILES) break;
        int mA = tA * 16, mB = mA + 16;
        const __half* pA = A + (size_t)(mA + lr) * RS + head * HK + lk;
        const __half* pB = A + (size_t)(mB + lr) * RS + head * HK + lk;

        f32x4 acc[2][2];
        #pragma unroll
        for (int i = 0; i < 2; ++i)
            #pragma unroll
            for (int c = 0; c < 2; ++c)
                acc[i][c] = (f32x4){0.f, 0.f, 0.f, 0.f};

        #pragma unroll
        for (int ks = 0; ks < KS; ++ks) {
            half8v aA = *(const half8v*)(pA + ks * 32);
            half8v aB = *(const half8v*)(pB + ks * 32);
            half8v b0 = *(const half8v*)((const char*)bs + ((( 0 + lr) * CB + lk * 2 + ks * 64) ^ swz));
            half8v b1 = *(const half8v*)((const char*)bs + (((16 + lr) * CB + lk * 2 + ks * 64) ^ swz));
            acc[0][0] = __builtin_amdgcn_mfma_f32_16x16x32_f16(aA, b0, acc[0][0], 0, 0, 0);
            acc[0][1] = __builtin_amdgcn_mfma_f32_16x16x32_f16(aA, b1, acc[0][1], 0, 0, 0);
            acc[1][0] = __builtin_amdgcn_mfma_f32_16x16x32_f16(aB, b0, acc[1][0], 0, 0, 0);
            acc[1][1] = __builtin_amdgcn_mfma_f32_16x16x32_f16(aB, b1, acc[1][1], 0, 0, 0);
        }

        int rbase = (lane >> 4) * 4;
        #pragma unroll
        for (int ti = 0; ti < 2; ++ti) {
            #pragma unroll
            for (int c = 0; c < 2; ++c)
                #pragma unroll
                for (int r = 0; r < 4; ++r)
                    cst[wid][(rbase + r) * 36 + c * 16 + lr] = __float2half(acc[ti][c][r]);
            int m0 = ti ? mB : mA;
            #pragma unroll
            for (int p = 0; p < 2; ++p) {
                int row = p * 8 + (lane >> 3), hb = lane & 7;
                float2 v = *(const float2*)((const char*)&cst[wid][0] + row * 72 + hb * 8);
                *(float2*)((char*)C + ((size_t)(m0 + row) * 1024 + n0) * 2 + hb * 8) = v;
            }
        }
    }
}

// ---------------------------------------------------------------- attention scalars
// layer1 es/ed (+ mkey init) from h0
__global__ __launch_bounds__(256) void k_esed1(const __half* __restrict__ h0f,
                                               const float* __restrict__ wa,
                                               const float* __restrict__ wd,
                                               float* __restrict__ es,
                                               float* __restrict__ ed,
                                               int* __restrict__ mkey) {
    int idx = blockIdx.x * 256 + threadIdx.x;   // n*4+h
    if (idx >= N_NODES * 4) return;
    int n = idx >> 2, h = idx & 3;
    float s = 0.f, d2 = 0.f;
    #pragma unroll
    for (int i = 0; i < 32; ++i) {
        float v = __half2float(h0f[n * 32 + i]);
        s  += v * wa[h * 32 + i];
        d2 += v * wd[h * 32 + i];
    }
    es[idx] = s; ed[idx] = d2;
    mkey[idx] = fkey(leaky(s + d2));
}

__global__ __launch_bounds__(256) void k_mmax(const int* __restrict__ ei,
                                              const float* __restrict__ es,
                                              const float* __restrict__ ed,
                                              int* __restrict__ mkey) {
    int idx = blockIdx.x * 256 + threadIdx.x;
    if (idx >= N_EDGES * 4) return;
    int e = idx >> 2, h = idx & 3;
    int src = ei[e], dst = ei[N_EDGES + e];
    atomicMax(&mkey[dst * 4 + h], fkey(leaky(es[src * 4 + h] + ed[dst * 4 + h])));
}

__global__ __launch_bounds__(256) void k_watt(const int* __restrict__ ei,
                                              const int* __restrict__ epos,
                                              const float* __restrict__ es,
                                              const float* __restrict__ ed,
                                              const int* __restrict__ mkey,
                                              float* __restrict__ wv,
                                              float* __restrict__ den) {
    int idx = blockIdx.x * 256 + threadIdx.x;
    if (idx >= N_EDGES * 4) return;
    int e = idx >> 2, h = idx & 3;
    int src = ei[e], dst = ei[N_EDGES + e];
    float v = leaky(es[src * 4 + h] + ed[dst * 4 + h]);
    float w = __expf(v - funkey(mkey[dst * 4 + h]));
    wv[(size_t)epos[e] * 4 + h] = w;
    atomicAdd(&den[dst * 4 + h], w);
}

// ---------------------------------------------------------------- pre-GEMM aggregation
__global__ __launch_bounds__(256) void k_agg1(const int* __restrict__ rowptr,
                                              const int* __restrict__ csrc,
                                              const float* __restrict__ es,
                                              const float* __restrict__ ed,
                                              const int* __restrict__ mkey,
                                              const float* __restrict__ denb,
                                              const float* __restrict__ wv,
                                              const __half* __restrict__ h0f,
                                              __half* __restrict__ agg0) {
    int dst = blockIdx.x * 4 + (threadIdx.x >> 6);
    if (dst >= N_NODES) return;
    int lane = threadIdx.x & 63;
    int h = lane >> 4, i2 = lane & 15;
    float m = funkey(mkey[dst * 4 + h]);
    float vself = leaky(es[dst * 4 + h] + ed[dst * 4 + h]);
    float ws = __expf(vself - m);
    float dn = denb[dst * 4 + h] + ws;
    int r0 = rowptr[dst], r1 = rowptr[dst + 1];

    __half2 hv = *(const __half2*)(h0f + (size_t)dst * 32 + i2 * 2);
    float2 f = __half22float2(hv);
    float ax = ws * f.x, ay = ws * f.y;
    for (int r = r0; r < r1; ++r) {
        int src = csrc[r];
        float w = wv[(size_t)r * 4 + h];
        __half2 sv = *(const __half2*)(h0f + (size_t)src * 32 + i2 * 2);
        float2 g = __half22float2(sv);
        ax += w * g.x; ay += w * g.y;
    }
    float inv = 1.f / (dn + 1e-16f);
    *(__half2*)(agg0 + (size_t)dst * 128 + h * 32 + i2 * 2) =
        __float22half2_rn(make_float2(ax * inv, ay * inv));
}

__global__ __launch_bounds__(256) void k_agg2(const int* __restrict__ rowptr,
                                              const int* __restrict__ csrc,
                                              const float* __restrict__ es,
                                              const float* __restrict__ ed,
                                              const int* __restrict__ mkey,
                                              const float* __restrict__ denb,
                                              const float* __restrict__ wv,
                                              const __half* __restrict__ h1f,
                                              __half* __restrict__ agg1) {
    int dst = blockIdx.x * 4 + (threadIdx.x >> 6);
    if (dst >= N_NODES) return;
    int lane = threadIdx.x & 63;
    float ws[4], dn[4];
    #pragma unroll
    for (int h = 0; h < 4; ++h) {
        float m = funkey(mkey[dst * 4 + h]);
        float vself = leaky(es[dst * 4 + h] + ed[dst * 4 + h]);
        ws[h] = __expf(vself - m);
        dn[h] = denb[dst * 4 + h] + ws[h];
    }
    int r0 = rowptr[dst], r1 = rowptr[dst + 1];

    float acc[4][4];
    {
        float2 q = *(const float2*)(h1f + (size_t)dst * 256 + lane * 4);
        const __half2* hq = (const __half2*)&q;
        float2 f0 = __half22float2(hq[0]), f1 = __half22float2(hq[1]);
        #pragma unroll
        for (int h = 0; h < 4; ++h) {
            acc[h][0] = ws[h] * f0.x; acc[h][1] = ws[h] * f0.y;
            acc[h][2] = ws[h] * f1.x; acc[h][3] = ws[h] * f1.y;
        }
    }
    for (int r = r0; r < r1; ++r) {
        int src = csrc[r];
        float4 w4 = *(const float4*)(wv + (size_t)r * 4);
        float2 q = *(const float2*)(h1f + (size_t)src * 256 + lane * 4);
        const __half2* hq = (const __half2*)&q;
        float2 f0 = __half22float2(hq[0]), f1 = __half22float2(hq[1]);
        acc[0][0] += w4.x * f0.x; acc[0][1] += w4.x * f0.y; acc[0][2] += w4.x * f1.x; acc[0][3] += w4.x * f1.y;
        acc[1][0] += w4.y * f0.x; acc[1][1] += w4.y * f0.y; acc[1][2] += w4.y * f1.x; acc[1][3] += w4.y * f1.y;
        acc[2][0] += w4.z * f0.x; acc[2][1] += w4.z * f0.y; acc[2][2] += w4.z * f1.x; acc[2][3] += w4.z * f1.y;
        acc[3][0] += w4.w * f0.x; acc[3][1] += w4.w * f0.y; acc[3][2] += w4.w * f1.x; acc[3][3] += w4.w * f1.y;
    }
    #pragma unroll
    for (int h = 0; h < 4; ++h) {
        float inv = 1.f / (dn[h] + 1e-16f);
        __half2 o0 = __float22half2_rn(make_float2(acc[h][0] * inv, acc[h][1] * inv));
        __half2 o1 = __float22half2_rn(make_float2(acc[h][2] * inv, acc[h][3] * inv));
        __half2* op = (__half2*)(agg1 + (size_t)dst * 1024 + h * 256 + lane * 4);
        op[0] = o0; op[1] = o1;
    }
}

// ---------------------------------------------------------------- finales
// fin1 fused with layer2 es/ed (+mkey): one block per node
__global__ __launch_bounds__(256) void k_fin1e(const __half* __restrict__ pre,
                                               const float* __restrict__ b,
                                               const float* __restrict__ wa,
                                               const float* __restrict__ wd,
                                               __half* __restrict__ h1f,
                                               float* __restrict__ es,
                                               float* __restrict__ ed,
                                               int* __restrict__ mkey) {
    __shared__ float row[256];
    int n = blockIdx.x, d = threadIdx.x;
    const __half* p = pre + (size_t)n * 1024 + d;
    float s = __half2float(p[0]) + __half2float(p[256]) + __half2float(p[512]) + __half2float(p[768]);
    float v = fmaxf(0.25f * s + b[d], 0.f);
    h1f[(size_t)n * 256 + d] = __float2half(v);
    row[d] = v;
    __syncthreads();
    int h = d >> 6, lane = d & 63;
    float ss = 0.f, dd = 0.f;
    #pragma unroll
    for (int q = 0; q < 4; ++q) {
        int dc = lane + q * 64;
        ss += row[dc] * wa[h * 256 + dc];
        dd += row[dc] * wd[h * 256 + dc];
    }
    #pragma unroll
    for (int off = 32; off; off >>= 1) {
        ss += __shfl_down(ss, off);
        dd += __shfl_down(dd, off);
    }
    if (lane == 0) {
        es[n * 4 + h] = ss; ed[n * 4 + h] = dd;
        mkey[n * 4 + h] = fkey(leaky(ss + dd));
    }
}

__global__ __launch_bounds__(256) void k_fin2(const __half* __restrict__ pre,
                                              const float* __restrict__ b,
                                              float* __restrict__ h2) {
    int idx = blockIdx.x * 256 + threadIdx.x;
    if (idx >= N_NODES * 256) return;
    int n = idx >> 8, d = idx & 255;
    const __half* p = pre + (size_t)n * 1024 + d;
    float s = __half2float(p[0]) + __half2float(p[256]) + __half2float(p[512]) + __half2float(p[768]);
    h2[idx] = fmaxf(0.25f * s + b[d], 0.f);
}

// ---------------------------------------------------------------- heads
__global__ __launch_bounds__(256) void k_wire(const int* __restrict__ wm,
                                              const float* __restrict__ h2,
                                              const float* __restrict__ ww,
                                              const float* __restrict__ wb,
                                              float* __restrict__ out) {
    int k = blockIdx.x * 4 + (threadIdx.x >> 6);
    int lane = threadIdx.x & 63;
    if (k >= KWIRE) return;
    int n = wm[k];
    float s = 0.f;
    for (int d = lane; d < 256; d += 64) s += h2[(size_t)n * 256 + d] * ww[d];
    #pragma unroll
    for (int off = 32; off; off >>= 1) s += __shfl_down(s, off);
    if (lane == 0) out[k] = s + wb[0];
}

__global__ __launch_bounds__(256) void k_pool(const float* __restrict__ h2,
                                              const int* __restrict__ batch,
                                              float* __restrict__ pooled,
                                              float* __restrict__ gcnt) {
    int n0 = blockIdx.x * POOL_NB;
    int n1 = n0 + POOL_NB; if (n1 > N_NODES) n1 = N_NODES;
    int d = threadIdx.x;
    int cur = batch[n0];
    float acc = 0.f, cnt = 0.f;
    for (int n = n0; n < n1; ++n) {
        int g = batch[n];
        if (g != cur) {
            atomicAdd(&pooled[cur * 256 + d], acc);
            if (d == 0) atomicAdd(&gcnt[cur], cnt);
            acc = 0.f; cnt = 0.f; cur = g;
        }
        acc += h2[(size_t)n * 256 + d];
        cnt += 1.f;
    }
    atomicAdd(&pooled[cur * 256 + d], acc);
    if (d == 0) atomicAdd(&gcnt[cur], cnt);
}

__global__ __launch_bounds__(256) void k_act(const float* __restrict__ pooled,
                                             const float* __restrict__ gcnt,
                                             const float* __restrict__ aw,
                                             const float* __restrict__ ab,
                                             float* __restrict__ out) {
    int u = blockIdx.x * 4 + (threadIdx.x >> 6);
    int lane = threadIdx.x & 63;
    if (u >= NGRAPH * NACT) return;
    int g = u >> 4, a = u & 15;
    float c = fmaxf(gcnt[g], 1.f);
    float s = 0.f;
    for (int d = lane; d < 256; d += 64) s += pooled[g * 256 + d] * aw[d * 16 + a];
    #pragma unroll
    for (int off = 32; off; off >>= 1) s += __shfl_down(s, off);
    if (lane == 0) out[KWIRE + u] = s / c + ab[a];
}

// ---------------------------------------------------------------- launch
extern "C" void kernel_launch(void* const* d_in, const int* in_sizes, int n_in,
                              void* d_out, int out_size, void* d_ws, size_t ws_size,
                              hipStream_t stream) {
    const float* x        = (const float*)d_in[0];
    const float* edge_attr= (const float*)d_in[1];
    const int*   wire_mask= (const int*)d_in[2];
    const int*   edge_idx = (const int*)d_in[3];
    const int*   batch    = (const int*)d_in[4];
    const float* enc_w1   = (const float*)d_in[5];
    const float* enc_b1   = (const float*)d_in[6];
    const float* enc_w2   = (const float*)d_in[7];
    const float* enc_b2   = (const float*)d_in[8];
    const float* root_w   = (const float*)d_in[9];
    const float* nn_bias  = (const float*)d_in[10];
    const float* gat1_w   = (const float*)d_in[11];
    const float* gat1_asrc= (const float*)d_in[12];
    const float* gat1_adst= (const float*)d_in[13];
    const float* gat1_b   = (const float*)d_in[14];
    const float* gat2_w   = (const float*)d_in[15];
    const float* gat2_asrc= (const float*)d_in[16];
    const float* gat2_adst= (const float*)d_in[17];
    const float* gat2_b   = (const float*)d_in[18];
    const float* wire_w   = (const float*)d_in[19];
    const float* wire_b   = (const float*)d_in[20];
    const float* act_w    = (const float*)d_in[21];
    const float* act_b    = (const float*)d_in[22];
    float* out = (float*)d_out;

    float* ws = (float*)d_ws;
    size_t off = 0;
    __half* big   = (__half*)(ws + off); off += (size_t)M_PAD * 1024 / 2;  // T16 -> pre1 -> pre2
    __half* agg1f = (__half*)(ws + off); off += (size_t)M_PAD * 1024 / 2;
    __half* agg0f = (__half*)(ws + off); off += (size_t)M_PAD * 128 / 2;
    __half* h0f   = (__half*)(ws + off); off += (size_t)M_PAD * 32 / 2;
    __half* h1f   = (__half*)(ws + off); off += (size_t)M_PAD * 256 / 2;
    __half* xf    = (__half*)(ws + off); off += (size_t)M_PAD * 32 / 2;
    __half* hEs   = (__half*)(ws + off); off += (size_t)N_EDGES * 32 / 2;
    float* xb     = ws + off; off += 800000;
    float* agg    = ws + off; off += 800000;
    float* esb    = ws + off; off += 100000;
    float* edb    = ws + off; off += 100000;
    float* h2     = ws + off; off += 6400000;
    float* pooled = ws + off; off += NGRAPH * 256;
    float* gcnt   = ws + off; off += NGRAPH;
    int* deg      = (int*)(ws + off); off += 25600;   // zero-region start
    int* deg2     = (int*)(ws + off); off += 25600;
    int* cursor   = (int*)(ws + off); off += 25600;
    int* cursor2  = (int*)(ws + off); off += 25600;   // zero-region end
    int* rowptr   = (int*)(ws + off); off += 25600;
    int* rowptr2  = (int*)(ws + off); off += 25600;
    int* csrc     = (int*)(ws + off); off += N_EDGES;
    int* epos     = (int*)(ws + off); off += N_EDGES;
    int* cdst     = (int*)(ws + off); off += N_EDGES;
    int* epos2    = (int*)(ws + off); off += N_EDGES;
    int* mkey     = (int*)(ws + off); off += 100000;
    float* den    = ws + off; off += 100000;
    float* wv     = ws + off; off += (size_t)N_EDGES * 4;
    __half* wt1   = (__half*)(ws + off); off += 16384;
    __half* wt2   = (__half*)(ws + off); off += 131072;
    __half* wtt   = (__half*)(ws + off); off += 16384;
    float* wa1    = ws + off; off += 128;
    float* wd1    = ws + off; off += 128;
    float* wa2    = ws + off; off += 1024;
    float* wd2    = ws + off; off += 1024;

    const int EH = N_EDGES * 4;
    const int GB = 3328;   // 8 xcd x 13 ygroups x 32 strips

    // ---- CSR build (both directions) ----
    hipMemsetAsync(deg, 0, 4 * 25600 * sizeof(int), stream);   // deg, deg2, cursor, cursor2
    k_deg2<<<(N_EDGES + 255) / 256, 256, 0, stream>>>(edge_idx, deg, deg2);
    k_scan2<<<2, 256, 0, stream>>>(deg, rowptr, deg2, rowptr2);
    k_scatter2<<<(N_EDGES + 255) / 256, 256, 0, stream>>>(edge_idx, rowptr, rowptr2,
                                                          cursor, cursor2, csrc, epos, cdst, epos2);

    // ---- weight prep ----
    k_wcvt<IN_DIM><<<(IN_DIM * 1024 + 255) / 256, 256, 0, stream>>>(gat1_w, wt1);
    k_wcvt<HIDD><<<(HIDD * 1024 + 255) / 256, 256, 0, stream>>>(gat2_w, wt2);
    k_w2perm<<<(32 * 1024 + 255) / 256, 256, 0, stream>>>(enc_w2, wtt);
    k_xcvt<<<(N_NODES * 32 + 255) / 256, 256, 0, stream>>>(x, enc_b2, xf, xb);
    k_wa1<<<1, 128, 0, stream>>>(gat1_w, gat1_asrc, gat1_adst, wa1, wd1);
    k_wa2<<<4, 256, 0, stream>>>(gat2_w, gat2_asrc, gat2_adst, wa2, wd2);

    // ---- NNConv ----
    hipMemsetAsync(agg, 0, 800000 * sizeof(float), stream);
    k_gemm<IN_DIM, 32, 0><<<GB, 256, 0, stream>>>(xf, wtt, big);      // T16
    k_hedge<<<(N_EDGES + 7) / 8, 256, 0, stream>>>(edge_attr, enc_w1, enc_b1, epos2, hEs);
    k_msg2<<<(N_NODES + 7) / 8, 256, 0, stream>>>(rowptr2, cdst, hEs, big, xb, agg);
    k_h0<<<(N_NODES + 7) / 8, 256, 0, stream>>>(x, root_w, nn_bias, agg, rowptr, h0f);

    // ---- GAT layer 1 ----
    k_esed1<<<(N_NODES * 4 + 255) / 256, 256, 0, stream>>>(h0f, wa1, wd1, esb, edb, mkey);
    k_mmax<<<(EH + 255) / 256, 256, 0, stream>>>(edge_idx, esb, edb, mkey);
    hipMemsetAsync(den, 0, 100000 * sizeof(float), stream);
    k_watt<<<(EH + 255) / 256, 256, 0, stream>>>(edge_idx, epos, esb, edb, mkey, wv, den);
    k_agg1<<<(N_NODES + 3) / 4, 256, 0, stream>>>(rowptr, csrc, esb, edb, mkey, den, wv, h0f, agg0f);
    k_gemm<IN_DIM, 128, 32><<<GB, 256, 0, stream>>>(agg0f, wt1, big);  // pre1
    k_fin1e<<<N_NODES, 256, 0, stream>>>(big, gat1_b, wa2, wd2, h1f, esb, edb, mkey);

    // ---- GAT layer 2 ----
    k_mmax<<<(EH + 255) / 256, 256, 0, stream>>>(edge_idx, esb, edb, mkey);
    hipMemsetAsync(den, 0, 100000 * sizeof(float), stream);
    k_watt<<<(EH + 255) / 256, 256, 0, stream>>>(edge_idx, epos, esb, edb, mkey, wv, den);
    k_agg2<<<(N_NODES + 3) / 4, 256, 0, stream>>>(rowptr, csrc, esb, edb, mkey, den, wv, h1f, agg1f);
    k_gemm<HIDD, 1024, 256><<<GB, 256, 0, stream>>>(agg1f, wt2, big);  // pre2
    k_fin2<<<(N_NODES * 256 + 255) / 256, 256, 0, stream>>>(big, gat2_b, h2);

    // ---- heads ----
    k_wire<<<KWIRE / 4, 256, 0, stream>>>(wire_mask, h2, wire_w, wire_b, out);
    hipMemsetAsync(pooled, 0, (NGRAPH * 256 + NGRAPH) * sizeof(float), stream);
    k_pool<<<(N_NODES + POOL_NB - 1) / POOL_NB, 256, 0, stream>>>(h2, batch, pooled, gcnt);
    k_act<<<NGRAPH * NACT / 4, 256, 0, stream>>>(pooled, gcnt, act_w, act_b, out);
}